// Round 1
// baseline (218.154 us; speedup 1.0000x reference)
//
#include <hip/hip_runtime.h>
#include <hip/hip_bf16.h>
#include <stdint.h>

#define DEVI __device__ __forceinline__

typedef unsigned short u16;
typedef __attribute__((ext_vector_type(8))) short short8;
typedef __attribute__((ext_vector_type(8))) __bf16 bf16x8;
typedef __attribute__((ext_vector_type(4))) float f32x4;

// ---------- small helpers ----------
DEVI u16 f2b(float f) {
  __hip_bfloat16 h = __float2bfloat16(f);
  return __builtin_bit_cast(u16, h);
}
DEVI float b2f(u16 u) {
  union { float f; uint32_t i; } v;
  v.i = ((uint32_t)u) << 16;
  return v.f;
}

DEVI f32x4 mfma16(short8 a, short8 b, f32x4 c) {
  return __builtin_amdgcn_mfma_f32_16x16x32_bf16(
      __builtin_bit_cast(bf16x8, a), __builtin_bit_cast(bf16x8, b), c, 0, 0, 0);
}

// async global->LDS, 16B per lane; LDS dest = wave-uniform base + lane*16
DEVI void gload_lds16(const u16* g, u16* l) {
  __builtin_amdgcn_global_load_lds(
      (const __attribute__((address_space(1))) uint32_t*)g,
      (__attribute__((address_space(3))) uint32_t*)l, 16, 0, 0);
}

// Swizzled ds_read_b128 of an MFMA fragment from a [rows][64] bf16 tile
// (row stride 128B). byte = row*128 + col16*16, XOR-swizzled by (row&7)<<4.
DEVI short8 lds_frag(const u16* base, int row, int col16) {
  int byte = (row << 7) ^ (col16 << 4) ^ ((row & 7) << 4);
  return *(const short8*)((const char*)base + byte);
}

// ---------- fp32 -> bf16 conversion of inputs ----------
DEVI ushort4 cvt4(float4 v) {
  ushort4 o;
  o.x = f2b(v.x); o.y = f2b(v.y); o.z = f2b(v.z); o.w = f2b(v.w);
  return o;
}

__global__ void cvt_kernel(const float4* __restrict__ x, const float4* __restrict__ wq,
                           const float4* __restrict__ wk, const float4* __restrict__ wv,
                           const float4* __restrict__ wo,
                           ushort4* __restrict__ xb, ushort4* __restrict__ wqb,
                           ushort4* __restrict__ wkb, ushort4* __restrict__ wvb,
                           ushort4* __restrict__ wob) {
  int t = blockIdx.x * blockDim.x + threadIdx.x;
  int stride = gridDim.x * blockDim.x;
  for (int i = t; i < 1048576; i += stride) xb[i]  = cvt4(x[i]);
  for (int i = t; i < 1048576; i += stride) wqb[i] = cvt4(wq[i]);
  for (int i = t; i < 262144;  i += stride) wkb[i] = cvt4(wk[i]);
  for (int i = t; i < 262144;  i += stride) wvb[i] = cvt4(wv[i]);
  for (int i = t; i < 1048576; i += stride) wob[i] = cvt4(wo[i]);
}

// ---------- QKV projection GEMM ----------
// C[s][n] = sum_e X[s][e] * W[n][e], M=2048, N=3072 (Q 0..2047, K ..2559, V ..3071)
// 128x128 tile, BK=64, 4 waves (2x2), 16x16x32 bf16 MFMA.
__global__ __launch_bounds__(256) void qkv_gemm(
    const u16* __restrict__ X, const u16* __restrict__ WQ,
    const u16* __restrict__ WK, const u16* __restrict__ WV,
    u16* __restrict__ Qo, u16* __restrict__ Ko, u16* __restrict__ VTo) {
  __shared__ __align__(16) u16 As[128 * 64];
  __shared__ __align__(16) u16 Bs[128 * 64];
  const int tid = threadIdx.x;
  const int l = tid & 63, w = tid >> 6;
  const int wm = w >> 1, wn = w & 1;
  const int bn = blockIdx.x, bm = blockIdx.y;

  const u16* Wsrc;
  int nbase;
  if (bn < 16)      { Wsrc = WQ; nbase = bn * 128; }
  else if (bn < 20) { Wsrc = WK; nbase = bn * 128 - 2048; }
  else              { Wsrc = WV; nbase = bn * 128 - 2560; }

  f32x4 acc[4][4];
#pragma unroll
  for (int i = 0; i < 4; ++i)
#pragma unroll
    for (int j = 0; j < 4; ++j) acc[i][j] = f32x4{0.f, 0.f, 0.f, 0.f};

  const u16* Abase = X + (size_t)bm * 128 * 2048;

  for (int kt = 0; kt < 32; ++kt) {
#pragma unroll
    for (int i = 0; i < 4; ++i) {
      int p = i * 256 + tid;
      int r = p >> 3;
      int c = (p & 7) ^ (r & 7);  // pre-swizzled source column (16B chunks)
      gload_lds16(Abase + (size_t)r * 2048 + kt * 64 + c * 8, As + p * 8);
      gload_lds16(Wsrc + (size_t)(nbase + r) * 2048 + kt * 64 + c * 8, Bs + p * 8);
    }
    __syncthreads();
#pragma unroll
    for (int kk = 0; kk < 2; ++kk) {
      short8 af[4], bfr[4];
#pragma unroll
      for (int mi = 0; mi < 4; ++mi)
        af[mi] = lds_frag(As, wm * 64 + mi * 16 + (l & 15), kk * 4 + (l >> 4));
#pragma unroll
      for (int ni = 0; ni < 4; ++ni)
        bfr[ni] = lds_frag(Bs, wn * 64 + ni * 16 + (l & 15), kk * 4 + (l >> 4));
#pragma unroll
      for (int mi = 0; mi < 4; ++mi)
#pragma unroll
        for (int ni = 0; ni < 4; ++ni)
          acc[mi][ni] = mfma16(af[mi], bfr[ni], acc[mi][ni]);
    }
    __syncthreads();
  }

#pragma unroll
  for (int mi = 0; mi < 4; ++mi) {
    int srow0 = bm * 128 + wm * 64 + mi * 16 + (l >> 4) * 4;
#pragma unroll
    for (int ni = 0; ni < 4; ++ni) {
      int n = nbase + wn * 64 + ni * 16 + (l & 15);
      f32x4 v = acc[mi][ni];
      if (bn < 16) {
#pragma unroll
        for (int r = 0; r < 4; ++r)
          Qo[(size_t)(srow0 + r) * 2048 + n] = f2b(v[r]);
      } else if (bn < 20) {
#pragma unroll
        for (int r = 0; r < 4; ++r)
          Ko[(size_t)(srow0 + r) * 512 + n] = f2b(v[r]);
      } else {
        // V written transposed: VT[d][s], 4 consecutive s per lane -> 8B store
        ushort4 pk;
        pk.x = f2b(v[0]); pk.y = f2b(v[1]); pk.z = f2b(v[2]); pk.w = f2b(v[3]);
        *(ushort4*)(VTo + (size_t)n * 2048 + srow0) = pk;
      }
    }
  }
}

// ---------- RoPE (in-place on bf16 Q and K; Q also scaled by 1/sqrt(64)) ----------
__global__ void rope_kernel(u16* __restrict__ Qb, u16* __restrict__ Kb) {
  int idx = blockIdx.x * blockDim.x + threadIdx.x;
  const int NQ = 2048 * 1024;
  const int NT = NQ + 2048 * 256;
  if (idx >= NT) return;
  u16* base;
  int s, p;
  float scale;
  if (idx < NQ) {
    s = idx >> 10; p = idx & 1023;
    base = Qb + (size_t)s * 2048 + p * 2;
    scale = 0.125f;
  } else {
    int j = idx - NQ;
    s = j >> 8; p = j & 255;
    base = Kb + (size_t)s * 512 + p * 2;
    scale = 1.0f;
  }
  int i = p & 31;  // pair index within head (HD=64 -> 32 pairs)
  // theta = 10000^(-2i/64) = exp2(-i * log2(10000)/32)
  float theta = exp2f(-(float)i * 0.41524101186092034f);
  float ang = (float)s * theta;
  float sn, cs;
  sincosf(ang, &sn, &cs);
  float x0 = b2f(base[0]), x1 = b2f(base[1]);
  u16 o0 = f2b((x0 * cs - x1 * sn) * scale);
  u16 o1 = f2b((x1 * cs + x0 * sn) * scale);
  base[0] = o0;
  base[1] = o1;
}

// ---------- causal flash attention ----------
// grid: (32 q-blocks, 32 heads), 256 threads. Each wave owns 16 q-rows.
__global__ __launch_bounds__(256) void attn_kernel(
    const u16* __restrict__ Qb, const u16* __restrict__ Kb,
    const u16* __restrict__ VTb, u16* __restrict__ AOb) {
  __shared__ __align__(16) u16 Ks[64 * 64];
  __shared__ __align__(16) u16 Vs[64 * 64];
  __shared__ __align__(16) u16 Ps[4][16 * 64];
  const int tid = threadIdx.x;
  const int l = tid & 63, w = tid >> 6;
  const int qb = 31 - (int)blockIdx.x;  // longest-running blocks first
  const int h = blockIdx.y;
  const int kvh = h >> 2;
  u16* pb = &Ps[w][0];

  // Q fragments held in registers (Q already scaled by 0.125 in rope_kernel)
  short8 aq[2];
  {
    const u16* qp = Qb + (size_t)(qb * 64 + w * 16 + (l & 15)) * 2048 + h * 64 + (l >> 4) * 8;
    aq[0] = *(const short8*)qp;
    aq[1] = *(const short8*)(qp + 32);
  }
  const int qrow0 = qb * 64 + w * 16 + (l >> 4) * 4;

  float m[4], lsum[4];
  f32x4 o[4];
#pragma unroll
  for (int r = 0; r < 4; ++r) { m[r] = -1e30f; lsum[r] = 0.f; }
#pragma unroll
  for (int dt = 0; dt < 4; ++dt) o[dt] = f32x4{0.f, 0.f, 0.f, 0.f};

  for (int kt = 0; kt <= qb; ++kt) {
    // stage K tile [64 k][64 d] and V^T tile [64 d][64 k], swizzled source
#pragma unroll
    for (int i = 0; i < 2; ++i) {
      int p = i * 256 + tid;
      int r = p >> 3;
      int c = (p & 7) ^ (r & 7);
      gload_lds16(Kb + (size_t)(kt * 64 + r) * 512 + kvh * 64 + c * 8, Ks + p * 8);
      gload_lds16(VTb + (size_t)(kvh * 64 + r) * 2048 + kt * 64 + c * 8, Vs + p * 8);
    }
    __syncthreads();

    // S = Q K^T (16 q-rows x 64 k-cols per wave)
    f32x4 s[4];
#pragma unroll
    for (int ck = 0; ck < 4; ++ck) s[ck] = f32x4{0.f, 0.f, 0.f, 0.f};
#pragma unroll
    for (int kk = 0; kk < 2; ++kk) {
#pragma unroll
      for (int ck = 0; ck < 4; ++ck) {
        short8 bk = lds_frag(Ks, ck * 16 + (l & 15), kk * 4 + (l >> 4));
        s[ck] = mfma16(aq[kk], bk, s[ck]);
      }
    }
    // causal mask on diagonal tile
    if (kt == qb) {
#pragma unroll
      for (int ck = 0; ck < 4; ++ck) {
        int kg = kt * 64 + ck * 16 + (l & 15);
#pragma unroll
        for (int r = 0; r < 4; ++r)
          if (kg > qrow0 + r) s[ck][r] = -1e30f;
      }
    }
    // online softmax: row = (l>>4)*4 + r, cols spread over (l&15) x 4 chunks
    float alpha[4];
#pragma unroll
    for (int r = 0; r < 4; ++r) {
      float t = fmaxf(fmaxf(s[0][r], s[1][r]), fmaxf(s[2][r], s[3][r]));
      t = fmaxf(t, __shfl_xor(t, 1));
      t = fmaxf(t, __shfl_xor(t, 2));
      t = fmaxf(t, __shfl_xor(t, 4));
      t = fmaxf(t, __shfl_xor(t, 8));
      float mn = fmaxf(m[r], t);
      alpha[r] = __expf(m[r] - mn);
      m[r] = mn;
    }
#pragma unroll
    for (int ck = 0; ck < 4; ++ck)
#pragma unroll
      for (int r = 0; r < 4; ++r) s[ck][r] = __expf(s[ck][r] - m[r]);
#pragma unroll
    for (int r = 0; r < 4; ++r) {
      float ps = s[0][r] + s[1][r] + s[2][r] + s[3][r];
      ps += __shfl_xor(ps, 1);
      ps += __shfl_xor(ps, 2);
      ps += __shfl_xor(ps, 4);
      ps += __shfl_xor(ps, 8);
      lsum[r] = lsum[r] * alpha[r] + ps;
    }
    // P -> bf16 -> per-wave LDS (swizzled), then reload as MFMA A-fragments
#pragma unroll
    for (int ck = 0; ck < 4; ++ck)
#pragma unroll
      for (int r = 0; r < 4; ++r) {
        int row = (l >> 4) * 4 + r;
        int col = ck * 16 + (l & 15);
        int byte = (row << 7) ^ (col << 1) ^ ((row & 7) << 4);
        *(u16*)((char*)pb + byte) = f2b(s[ck][r]);
      }
#pragma unroll
    for (int dt = 0; dt < 4; ++dt) {
      o[dt][0] *= alpha[0];
      o[dt][1] *= alpha[1];
      o[dt][2] *= alpha[2];
      o[dt][3] *= alpha[3];
    }
#pragma unroll
    for (int kk = 0; kk < 2; ++kk) {
      short8 pa = lds_frag(pb, l & 15, kk * 4 + (l >> 4));
#pragma unroll
      for (int dt = 0; dt < 4; ++dt) {
        short8 bv = lds_frag(Vs, dt * 16 + (l & 15), kk * 4 + (l >> 4));
        o[dt] = mfma16(pa, bv, o[dt]);
      }
    }
    __syncthreads();
  }

#pragma unroll
  for (int dt = 0; dt < 4; ++dt)
#pragma unroll
    for (int r = 0; r < 4; ++r) {
      float v = o[dt][r] / lsum[r];
      AOb[(size_t)(qrow0 + r) * 2048 + h * 64 + dt * 16 + (l & 15)] = f2b(v);
    }
}

// ---------- output projection GEMM (bf16 in, fp32 out) ----------
__global__ __launch_bounds__(256) void out_gemm(
    const u16* __restrict__ A, const u16* __restrict__ W, float* __restrict__ C) {
  __shared__ __align__(16) u16 As[128 * 64];
  __shared__ __align__(16) u16 Bs[128 * 64];
  const int tid = threadIdx.x;
  const int l = tid & 63, w = tid >> 6;
  const int wm = w >> 1, wn = w & 1;
  const int bn = blockIdx.x, bm = blockIdx.y;

  f32x4 acc[4][4];
#pragma unroll
  for (int i = 0; i < 4; ++i)
#pragma unroll
    for (int j = 0; j < 4; ++j) acc[i][j] = f32x4{0.f, 0.f, 0.f, 0.f};

  const u16* Abase = A + (size_t)bm * 128 * 2048;
  const u16* Bbase = W + (size_t)bn * 128 * 2048;

  for (int kt = 0; kt < 32; ++kt) {
#pragma unroll
    for (int i = 0; i < 4; ++i) {
      int p = i * 256 + tid;
      int r = p >> 3;
      int c = (p & 7) ^ (r & 7);
      gload_lds16(Abase + (size_t)r * 2048 + kt * 64 + c * 8, As + p * 8);
      gload_lds16(Bbase + (size_t)r * 2048 + kt * 64 + c * 8, Bs + p * 8);
    }
    __syncthreads();
#pragma unroll
    for (int kk = 0; kk < 2; ++kk) {
      short8 af[4], bfr[4];
#pragma unroll
      for (int mi = 0; mi < 4; ++mi)
        af[mi] = lds_frag(As, wm * 64 + mi * 16 + (l & 15), kk * 4 + (l >> 4));
#pragma unroll
      for (int ni = 0; ni < 4; ++ni)
        bfr[ni] = lds_frag(Bs, wn * 64 + ni * 16 + (l & 15), kk * 4 + (l >> 4));
#pragma unroll
      for (int mi = 0; mi < 4; ++mi)
#pragma unroll
        for (int ni = 0; ni < 4; ++ni)
          acc[mi][ni] = mfma16(af[mi], bfr[ni], acc[mi][ni]);
    }
    __syncthreads();
  }

#pragma unroll
  for (int mi = 0; mi < 4; ++mi) {
    int srow0 = bm * 128 + wm * 64 + mi * 16 + (l >> 4) * 4;
#pragma unroll
    for (int ni = 0; ni < 4; ++ni) {
      int n = bn * 128 + wn * 64 + ni * 16 + (l & 15);
#pragma unroll
      for (int r = 0; r < 4; ++r)
        C[(size_t)(srow0 + r) * 2048 + n] = acc[mi][ni][r];
    }
  }
}

// ---------- launch ----------
extern "C" void kernel_launch(void* const* d_in, const int* in_sizes, int n_in,
                              void* d_out, int out_size, void* d_ws, size_t ws_size,
                              hipStream_t stream) {
  (void)in_sizes; (void)n_in; (void)out_size; (void)ws_size;
  const float* x  = (const float*)d_in[0];
  const float* wq = (const float*)d_in[1];
  const float* wk = (const float*)d_in[2];
  const float* wv = (const float*)d_in[3];
  const float* wo = (const float*)d_in[4];
  float* out = (float*)d_out;
  char* ws = (char*)d_ws;

  // ws layout (bytes): 48 MiB total
  u16* xbf  = (u16*)(ws + 0);          // 8 MiB  x bf16 [2048][2048]
  u16* wqbf = (u16*)(ws + 8388608);    // 8 MiB
  u16* wkbf = (u16*)(ws + 16777216);   // 2 MiB
  u16* wvbf = (u16*)(ws + 18874368);   // 2 MiB
  u16* wobf = (u16*)(ws + 20971520);   // 8 MiB
  u16* Qb   = (u16*)(ws + 29360128);   // 8 MiB  Q bf16 [2048][2048] (roped, scaled)
  u16* Kb   = (u16*)(ws + 37748736);   // 2 MiB  K bf16 [2048][512]  (roped)
  u16* VTb  = (u16*)(ws + 39845888);   // 2 MiB  V^T bf16 [512][2048]
  u16* AOb  = (u16*)(ws + 41943040);   // 8 MiB  attn out bf16 [2048][2048]

  cvt_kernel<<<2048, 256, 0, stream>>>(
      (const float4*)x, (const float4*)wq, (const float4*)wk,
      (const float4*)wv, (const float4*)wo,
      (ushort4*)xbf, (ushort4*)wqbf, (ushort4*)wkbf, (ushort4*)wvbf, (ushort4*)wobf);

  qkv_gemm<<<dim3(24, 16), 256, 0, stream>>>(xbf, wqbf, wkbf, wvbf, Qb, Kb, VTb);

  rope_kernel<<<(2048 * 1024 + 2048 * 256 + 255) / 256, 256, 0, stream>>>(Qb, Kb);

  attn_kernel<<<dim3(32, 32), 256, 0, stream>>>(Qb, Kb, VTb, AOb);

  out_gemm<<<dim3(16, 16), 256, 0, stream>>>(AOb, wobf, out);
}

// Round 2
// 212.903 us; speedup vs baseline: 1.0247x; 1.0247x over previous
//
#include <hip/hip_runtime.h>
#include <hip/hip_bf16.h>
#include <stdint.h>

#define DEVI __device__ __forceinline__

typedef unsigned short u16;
typedef __attribute__((ext_vector_type(8))) short short8;
typedef __attribute__((ext_vector_type(8))) __bf16 bf16x8;
typedef __attribute__((ext_vector_type(4))) float f32x4;

// ---------- small helpers ----------
DEVI u16 f2b(float f) {
  __hip_bfloat16 h = __float2bfloat16(f);
  return __builtin_bit_cast(u16, h);
}
DEVI float b2f(u16 u) {
  union { float f; uint32_t i; } v;
  v.i = ((uint32_t)u) << 16;
  return v.f;
}

DEVI f32x4 mfma16(short8 a, short8 b, f32x4 c) {
  return __builtin_amdgcn_mfma_f32_16x16x32_bf16(
      __builtin_bit_cast(bf16x8, a), __builtin_bit_cast(bf16x8, b), c, 0, 0, 0);
}

// async global->LDS, 16B per lane; LDS dest = wave-uniform base + lane*16
DEVI void gload_lds16(const u16* g, u16* l) {
  __builtin_amdgcn_global_load_lds(
      (const __attribute__((address_space(1))) uint32_t*)g,
      (__attribute__((address_space(3))) uint32_t*)l, 16, 0, 0);
}

// Swizzled ds_read_b128 of an MFMA fragment from a [rows][64] bf16 tile
// (row stride 128B). byte = row*128 + col16*16, XOR-swizzled by (row&7)<<4.
DEVI short8 lds_frag(const u16* base, int row, int col16) {
  int byte = (row << 7) ^ (col16 << 4) ^ ((row & 7) << 4);
  return *(const short8*)((const char*)base + byte);
}

// ---------- fp32 -> bf16 conversion of inputs ----------
DEVI ushort4 cvt4(float4 v) {
  ushort4 o;
  o.x = f2b(v.x); o.y = f2b(v.y); o.z = f2b(v.z); o.w = f2b(v.w);
  return o;
}

__global__ void cvt_kernel(const float4* __restrict__ x, const float4* __restrict__ wq,
                           const float4* __restrict__ wk, const float4* __restrict__ wv,
                           const float4* __restrict__ wo,
                           ushort4* __restrict__ xb, ushort4* __restrict__ wqb,
                           ushort4* __restrict__ wkb, ushort4* __restrict__ wvb,
                           ushort4* __restrict__ wob) {
  int t = blockIdx.x * blockDim.x + threadIdx.x;
  int stride = gridDim.x * blockDim.x;
  for (int i = t; i < 1048576; i += stride) xb[i]  = cvt4(x[i]);
  for (int i = t; i < 1048576; i += stride) wqb[i] = cvt4(wq[i]);
  for (int i = t; i < 262144;  i += stride) wkb[i] = cvt4(wk[i]);
  for (int i = t; i < 262144;  i += stride) wvb[i] = cvt4(wv[i]);
  for (int i = t; i < 1048576; i += stride) wob[i] = cvt4(wo[i]);
}

// ---------- QKV projection GEMM ----------
// C[s][n] = sum_e X[s][e] * W[n][e], M=2048, N=3072 (Q 0..2047, K ..2559, V ..3071)
// 128x128 tile, BK=64, 4 waves (2x2), 16x16x32 bf16 MFMA.
__global__ __launch_bounds__(256) void qkv_gemm(
    const u16* __restrict__ X, const u16* __restrict__ WQ,
    const u16* __restrict__ WK, const u16* __restrict__ WV,
    u16* __restrict__ Qo, u16* __restrict__ Ko, u16* __restrict__ VTo) {
  __shared__ __align__(16) u16 As[128 * 64];
  __shared__ __align__(16) u16 Bs[128 * 64];
  const int tid = threadIdx.x;
  const int l = tid & 63, w = tid >> 6;
  const int wm = w >> 1, wn = w & 1;
  const int bn = blockIdx.x, bm = blockIdx.y;

  const u16* Wsrc;
  int nbase;
  if (bn < 16)      { Wsrc = WQ; nbase = bn * 128; }
  else if (bn < 20) { Wsrc = WK; nbase = bn * 128 - 2048; }
  else              { Wsrc = WV; nbase = bn * 128 - 2560; }

  f32x4 acc[4][4];
#pragma unroll
  for (int i = 0; i < 4; ++i)
#pragma unroll
    for (int j = 0; j < 4; ++j) acc[i][j] = f32x4{0.f, 0.f, 0.f, 0.f};

  const u16* Abase = X + (size_t)bm * 128 * 2048;

  for (int kt = 0; kt < 32; ++kt) {
#pragma unroll
    for (int i = 0; i < 4; ++i) {
      int p = i * 256 + tid;
      int r = p >> 3;
      int c = (p & 7) ^ (r & 7);  // pre-swizzled source column (16B chunks)
      gload_lds16(Abase + (size_t)r * 2048 + kt * 64 + c * 8, As + p * 8);
      gload_lds16(Wsrc + (size_t)(nbase + r) * 2048 + kt * 64 + c * 8, Bs + p * 8);
    }
    __syncthreads();
#pragma unroll
    for (int kk = 0; kk < 2; ++kk) {
      short8 af[4], bfr[4];
#pragma unroll
      for (int mi = 0; mi < 4; ++mi)
        af[mi] = lds_frag(As, wm * 64 + mi * 16 + (l & 15), kk * 4 + (l >> 4));
#pragma unroll
      for (int ni = 0; ni < 4; ++ni)
        bfr[ni] = lds_frag(Bs, wn * 64 + ni * 16 + (l & 15), kk * 4 + (l >> 4));
#pragma unroll
      for (int mi = 0; mi < 4; ++mi)
#pragma unroll
        for (int ni = 0; ni < 4; ++ni)
          acc[mi][ni] = mfma16(af[mi], bfr[ni], acc[mi][ni]);
    }
    __syncthreads();
  }

#pragma unroll
  for (int mi = 0; mi < 4; ++mi) {
    int srow0 = bm * 128 + wm * 64 + mi * 16 + (l >> 4) * 4;
#pragma unroll
    for (int ni = 0; ni < 4; ++ni) {
      int n = nbase + wn * 64 + ni * 16 + (l & 15);
      f32x4 v = acc[mi][ni];
      if (bn < 16) {
#pragma unroll
        for (int r = 0; r < 4; ++r)
          Qo[(size_t)(srow0 + r) * 2048 + n] = f2b(v[r]);
      } else if (bn < 20) {
#pragma unroll
        for (int r = 0; r < 4; ++r)
          Ko[(size_t)(srow0 + r) * 512 + n] = f2b(v[r]);
      } else {
        // V written transposed: VT[d][s], 4 consecutive s per lane -> 8B store
        ushort4 pk;
        pk.x = f2b(v[0]); pk.y = f2b(v[1]); pk.z = f2b(v[2]); pk.w = f2b(v[3]);
        *(ushort4*)(VTo + (size_t)n * 2048 + srow0) = pk;
      }
    }
  }
}

// ---------- RoPE (in-place on bf16 Q and K; Q also scaled by 1/sqrt(64)) ----------
__global__ void rope_kernel(u16* __restrict__ Qb, u16* __restrict__ Kb) {
  int idx = blockIdx.x * blockDim.x + threadIdx.x;
  const int NQ = 2048 * 1024;
  const int NT = NQ + 2048 * 256;
  if (idx >= NT) return;
  u16* base;
  int s, p;
  float scale;
  if (idx < NQ) {
    s = idx >> 10; p = idx & 1023;
    base = Qb + (size_t)s * 2048 + p * 2;
    scale = 0.125f;
  } else {
    int j = idx - NQ;
    s = j >> 8; p = j & 255;
    base = Kb + (size_t)s * 512 + p * 2;
    scale = 1.0f;
  }
  int i = p & 31;  // pair index within head (HD=64 -> 32 pairs)
  // theta = 10000^(-2i/64) = exp2(-i * log2(10000)/32)
  float theta = exp2f(-(float)i * 0.41524101186092034f);
  float ang = (float)s * theta;
  float sn, cs;
  sincosf(ang, &sn, &cs);
  float x0 = b2f(base[0]), x1 = b2f(base[1]);
  u16 o0 = f2b((x0 * cs - x1 * sn) * scale);
  u16 o1 = f2b((x1 * cs + x0 * sn) * scale);
  base[0] = o0;
  base[1] = o1;
}

// ---------- causal flash attention (GQA-shared K/V staging) ----------
// grid: (64 q-blocks of 32 rows, 8 kv-heads), 256 threads = 4 waves.
// Wave w handles q-head kvh*4+w; all 4 waves share one K/V tile per stage.
// Double-buffered K/V; one __syncthreads per k-tile.
DEVI void stage_kv(const u16* __restrict__ Kb, const u16* __restrict__ VTb,
                   u16* Ksb, u16* Vsb, int kvh, int t, int tid) {
#pragma unroll
  for (int i = 0; i < 2; ++i) {
    int p = i * 256 + tid;
    int r = p >> 3;
    int c = (p & 7) ^ (r & 7);  // pre-swizzled source (16B chunks)
    gload_lds16(Kb + (size_t)(t * 64 + r) * 512 + kvh * 64 + c * 8, Ksb + p * 8);
    gload_lds16(VTb + (size_t)(kvh * 64 + r) * 2048 + t * 64 + c * 8, Vsb + p * 8);
  }
}

__global__ __launch_bounds__(256) void attn_kernel(
    const u16* __restrict__ Qb, const u16* __restrict__ Kb,
    const u16* __restrict__ VTb, u16* __restrict__ AOb) {
  __shared__ __align__(16) u16 Ks[2][64 * 64];
  __shared__ __align__(16) u16 Vs[2][64 * 64];
  __shared__ __align__(16) u16 Ps[4][32 * 64];
  const int tid = threadIdx.x;
  const int l = tid & 63, w = tid >> 6;
  const int qb = 63 - (int)blockIdx.x;  // longest-running blocks first
  const int kvh = blockIdx.y;
  const int h = kvh * 4 + w;
  const int qs = qb * 32;
  u16* pb = &Ps[w][0];

  // Q fragments in registers (Q already roped + scaled by 0.125)
  short8 aq[2][2];
#pragma unroll
  for (int mi = 0; mi < 2; ++mi) {
    const u16* qp = Qb + (size_t)(qs + mi * 16 + (l & 15)) * 2048 + h * 64 + (l >> 4) * 8;
    aq[mi][0] = *(const short8*)qp;
    aq[mi][1] = *(const short8*)(qp + 32);
  }
  const int qr0 = (l >> 4) * 4;  // accumulator row offset within a 16-frag

  float m[2][4], ls[2][4];
  f32x4 o[2][4];
#pragma unroll
  for (int mi = 0; mi < 2; ++mi)
#pragma unroll
    for (int r = 0; r < 4; ++r) { m[mi][r] = -1e30f; ls[mi][r] = 0.f; }
#pragma unroll
  for (int mi = 0; mi < 2; ++mi)
#pragma unroll
    for (int dt = 0; dt < 4; ++dt) o[mi][dt] = f32x4{0.f, 0.f, 0.f, 0.f};

  const int nt = (qb >> 1) + 1;  // k-tiles: ((qs+31)>>6)+1

  stage_kv(Kb, VTb, Ks[0], Vs[0], kvh, 0, tid);
  __syncthreads();

  for (int t = 0; t < nt; ++t) {
    const int cur = t & 1;
    if (t + 1 < nt) stage_kv(Kb, VTb, Ks[cur ^ 1], Vs[cur ^ 1], kvh, t + 1, tid);

    // S = Q K^T : 32 q-rows x 64 k-cols per wave
    f32x4 s[2][4];
#pragma unroll
    for (int mi = 0; mi < 2; ++mi)
#pragma unroll
      for (int ck = 0; ck < 4; ++ck) s[mi][ck] = f32x4{0.f, 0.f, 0.f, 0.f};
    __builtin_amdgcn_s_setprio(1);
#pragma unroll
    for (int kk = 0; kk < 2; ++kk)
#pragma unroll
      for (int ck = 0; ck < 4; ++ck) {
        short8 bk = lds_frag(&Ks[cur][0], ck * 16 + (l & 15), kk * 4 + (l >> 4));
#pragma unroll
        for (int mi = 0; mi < 2; ++mi)
          s[mi][ck] = mfma16(aq[mi][kk], bk, s[mi][ck]);
      }
    __builtin_amdgcn_s_setprio(0);

    // causal mask on the last (diagonal) tile
    if (t == nt - 1) {
#pragma unroll
      for (int mi = 0; mi < 2; ++mi)
#pragma unroll
        for (int ck = 0; ck < 4; ++ck) {
          int kg = t * 64 + ck * 16 + (l & 15);
          int rg = qs + mi * 16 + qr0;
#pragma unroll
          for (int r = 0; r < 4; ++r)
            if (kg > rg + r) s[mi][ck][r] = -1e30f;
        }
    }

    // online softmax (rows spread over (l>>4)*4+r; cols over (l&15) x 4 chunks)
    float alpha[2][4];
#pragma unroll
    for (int mi = 0; mi < 2; ++mi)
#pragma unroll
      for (int r = 0; r < 4; ++r) {
        float t0 = fmaxf(fmaxf(s[mi][0][r], s[mi][1][r]), fmaxf(s[mi][2][r], s[mi][3][r]));
        t0 = fmaxf(t0, __shfl_xor(t0, 1));
        t0 = fmaxf(t0, __shfl_xor(t0, 2));
        t0 = fmaxf(t0, __shfl_xor(t0, 4));
        t0 = fmaxf(t0, __shfl_xor(t0, 8));
        float mn = fmaxf(m[mi][r], t0);
        alpha[mi][r] = __expf(m[mi][r] - mn);
        m[mi][r] = mn;
      }
#pragma unroll
    for (int mi = 0; mi < 2; ++mi)
#pragma unroll
      for (int ck = 0; ck < 4; ++ck)
#pragma unroll
        for (int r = 0; r < 4; ++r) s[mi][ck][r] = __expf(s[mi][ck][r] - m[mi][r]);
#pragma unroll
    for (int mi = 0; mi < 2; ++mi)
#pragma unroll
      for (int r = 0; r < 4; ++r) {
        float ps = s[mi][0][r] + s[mi][1][r] + s[mi][2][r] + s[mi][3][r];
        ps += __shfl_xor(ps, 1);
        ps += __shfl_xor(ps, 2);
        ps += __shfl_xor(ps, 4);
        ps += __shfl_xor(ps, 8);
        ls[mi][r] = ls[mi][r] * alpha[mi][r] + ps;
      }

    // P -> bf16 -> per-wave LDS (swizzled)
#pragma unroll
    for (int mi = 0; mi < 2; ++mi)
#pragma unroll
      for (int ck = 0; ck < 4; ++ck)
#pragma unroll
        for (int r = 0; r < 4; ++r) {
          int row = mi * 16 + qr0 + r;
          int col = ck * 16 + (l & 15);
          int byte = (row << 7) ^ (col << 1) ^ ((row & 7) << 4);
          *(u16*)((char*)pb + byte) = f2b(s[mi][ck][r]);
        }

    // rescale O
#pragma unroll
    for (int mi = 0; mi < 2; ++mi)
#pragma unroll
      for (int dt = 0; dt < 4; ++dt)
#pragma unroll
        for (int r = 0; r < 4; ++r) o[mi][dt][r] *= alpha[mi][r];

    // O += P V (A-frags from per-wave P, B-frags from shared V^T tile)
    __builtin_amdgcn_s_setprio(1);
#pragma unroll
    for (int kk = 0; kk < 2; ++kk) {
      short8 pa[2];
#pragma unroll
      for (int mi = 0; mi < 2; ++mi)
        pa[mi] = lds_frag(pb, mi * 16 + (l & 15), kk * 4 + (l >> 4));
#pragma unroll
      for (int dt = 0; dt < 4; ++dt) {
        short8 bv = lds_frag(&Vs[cur][0], dt * 16 + (l & 15), kk * 4 + (l >> 4));
#pragma unroll
        for (int mi = 0; mi < 2; ++mi)
          o[mi][dt] = mfma16(pa[mi], bv, o[mi][dt]);
      }
    }
    __builtin_amdgcn_s_setprio(0);

    __syncthreads();
  }

#pragma unroll
  for (int mi = 0; mi < 2; ++mi)
#pragma unroll
    for (int dt = 0; dt < 4; ++dt)
#pragma unroll
      for (int r = 0; r < 4; ++r) {
        float v = o[mi][dt][r] / ls[mi][r];
        AOb[(size_t)(qs + mi * 16 + qr0 + r) * 2048 + h * 64 + dt * 16 + (l & 15)] = f2b(v);
      }
}

// ---------- output projection GEMM (bf16 in, fp32 out) ----------
__global__ __launch_bounds__(256) void out_gemm(
    const u16* __restrict__ A, const u16* __restrict__ W, float* __restrict__ C) {
  __shared__ __align__(16) u16 As[128 * 64];
  __shared__ __align__(16) u16 Bs[128 * 64];
  const int tid = threadIdx.x;
  const int l = tid & 63, w = tid >> 6;
  const int wm = w >> 1, wn = w & 1;
  const int bn = blockIdx.x, bm = blockIdx.y;

  f32x4 acc[4][4];
#pragma unroll
  for (int i = 0; i < 4; ++i)
#pragma unroll
    for (int j = 0; j < 4; ++j) acc[i][j] = f32x4{0.f, 0.f, 0.f, 0.f};

  const u16* Abase = A + (size_t)bm * 128 * 2048;
  const u16* Bbase = W + (size_t)bn * 128 * 2048;

  for (int kt = 0; kt < 32; ++kt) {
#pragma unroll
    for (int i = 0; i < 4; ++i) {
      int p = i * 256 + tid;
      int r = p >> 3;
      int c = (p & 7) ^ (r & 7);
      gload_lds16(Abase + (size_t)r * 2048 + kt * 64 + c * 8, As + p * 8);
      gload_lds16(Bbase + (size_t)r * 2048 + kt * 64 + c * 8, Bs + p * 8);
    }
    __syncthreads();
#pragma unroll
    for (int kk = 0; kk < 2; ++kk) {
      short8 af[4], bfr[4];
#pragma unroll
      for (int mi = 0; mi < 4; ++mi)
        af[mi] = lds_frag(As, wm * 64 + mi * 16 + (l & 15), kk * 4 + (l >> 4));
#pragma unroll
      for (int ni = 0; ni < 4; ++ni)
        bfr[ni] = lds_frag(Bs, wn * 64 + ni * 16 + (l & 15), kk * 4 + (l >> 4));
#pragma unroll
      for (int mi = 0; mi < 4; ++mi)
#pragma unroll
        for (int ni = 0; ni < 4; ++ni)
          acc[mi][ni] = mfma16(af[mi], bfr[ni], acc[mi][ni]);
    }
    __syncthreads();
  }

#pragma unroll
  for (int mi = 0; mi < 4; ++mi) {
    int srow0 = bm * 128 + wm * 64 + mi * 16 + (l >> 4) * 4;
#pragma unroll
    for (int ni = 0; ni < 4; ++ni) {
      int n = bn * 128 + wn * 64 + ni * 16 + (l & 15);
#pragma unroll
      for (int r = 0; r < 4; ++r)
        C[(size_t)(srow0 + r) * 2048 + n] = acc[mi][ni][r];
    }
  }
}

// ---------- launch ----------
extern "C" void kernel_launch(void* const* d_in, const int* in_sizes, int n_in,
                              void* d_out, int out_size, void* d_ws, size_t ws_size,
                              hipStream_t stream) {
  (void)in_sizes; (void)n_in; (void)out_size; (void)ws_size;
  const float* x  = (const float*)d_in[0];
  const float* wq = (const float*)d_in[1];
  const float* wk = (const float*)d_in[2];
  const float* wv = (const float*)d_in[3];
  const float* wo = (const float*)d_in[4];
  float* out = (float*)d_out;
  char* ws = (char*)d_ws;

  // ws layout (bytes): 48 MiB total
  u16* xbf  = (u16*)(ws + 0);          // 8 MiB  x bf16 [2048][2048]
  u16* wqbf = (u16*)(ws + 8388608);    // 8 MiB
  u16* wkbf = (u16*)(ws + 16777216);   // 2 MiB
  u16* wvbf = (u16*)(ws + 18874368);   // 2 MiB
  u16* wobf = (u16*)(ws + 20971520);   // 8 MiB
  u16* Qb   = (u16*)(ws + 29360128);   // 8 MiB  Q bf16 [2048][2048] (roped, scaled)
  u16* Kb   = (u16*)(ws + 37748736);   // 2 MiB  K bf16 [2048][512]  (roped)
  u16* VTb  = (u16*)(ws + 39845888);   // 2 MiB  V^T bf16 [512][2048]
  u16* AOb  = (u16*)(ws + 41943040);   // 8 MiB  attn out bf16 [2048][2048]

  cvt_kernel<<<2048, 256, 0, stream>>>(
      (const float4*)x, (const float4*)wq, (const float4*)wk,
      (const float4*)wv, (const float4*)wo,
      (ushort4*)xbf, (ushort4*)wqbf, (ushort4*)wkbf, (ushort4*)wvbf, (ushort4*)wobf);

  qkv_gemm<<<dim3(24, 16), 256, 0, stream>>>(xbf, wqbf, wkbf, wvbf, Qb, Kb, VTb);

  rope_kernel<<<(2048 * 1024 + 2048 * 256 + 255) / 256, 256, 0, stream>>>(Qb, Kb);

  attn_kernel<<<dim3(64, 8), 256, 0, stream>>>(Qb, Kb, VTb, AOb);

  out_gemm<<<dim3(16, 16), 256, 0, stream>>>(AOb, wobf, out);
}

// Round 3
// 170.070 us; speedup vs baseline: 1.2827x; 1.2519x over previous
//
#include <hip/hip_runtime.h>
#include <hip/hip_bf16.h>
#include <stdint.h>

#define DEVI __device__ __forceinline__

typedef unsigned short u16;
typedef __attribute__((ext_vector_type(8))) short short8;
typedef __attribute__((ext_vector_type(8))) __bf16 bf16x8;
typedef __attribute__((ext_vector_type(4))) float f32x4;

// ---------- small helpers ----------
DEVI u16 f2b(float f) {
  __hip_bfloat16 h = __float2bfloat16(f);
  return __builtin_bit_cast(u16, h);
}
DEVI float b2f(u16 u) {
  union { float f; uint32_t i; } v;
  v.i = ((uint32_t)u) << 16;
  return v.f;
}
DEVI uint32_t pkbf(float a, float b) {
  return (uint32_t)f2b(a) | ((uint32_t)f2b(b) << 16);
}

DEVI f32x4 mfma16(short8 a, short8 b, f32x4 c) {
  return __builtin_amdgcn_mfma_f32_16x16x32_bf16(
      __builtin_bit_cast(bf16x8, a), __builtin_bit_cast(bf16x8, b), c, 0, 0, 0);
}

// async global->LDS, 16B per lane; LDS dest = wave-uniform base + lane*16
DEVI void gload_lds16(const u16* g, u16* l) {
  __builtin_amdgcn_global_load_lds(
      (const __attribute__((address_space(1))) uint32_t*)g,
      (__attribute__((address_space(3))) uint32_t*)l, 16, 0, 0);
}

// Swizzled ds_read_b128 of an MFMA fragment from a [rows][64] bf16 tile
// (row stride 128B). byte = row*128 + col16*16, XOR-swizzled by (row&7)<<4.
DEVI short8 lds_frag(const u16* base, int row, int col16) {
  int byte = (row << 7) ^ (col16 << 4) ^ ((row & 7) << 4);
  return *(const short8*)((const char*)base + byte);
}

// ---------- fp32 -> bf16 conversion of inputs ----------
DEVI ushort4 cvt4(float4 v) {
  ushort4 o;
  o.x = f2b(v.x); o.y = f2b(v.y); o.z = f2b(v.z); o.w = f2b(v.w);
  return o;
}

__global__ void cvt_kernel(const float4* __restrict__ x, const float4* __restrict__ wq,
                           const float4* __restrict__ wk, const float4* __restrict__ wv,
                           const float4* __restrict__ wo,
                           ushort4* __restrict__ xb, ushort4* __restrict__ wqb,
                           ushort4* __restrict__ wkb, ushort4* __restrict__ wvb,
                           ushort4* __restrict__ wob) {
  int t = blockIdx.x * blockDim.x + threadIdx.x;
  int stride = gridDim.x * blockDim.x;
  for (int i = t; i < 1048576; i += stride) xb[i]  = cvt4(x[i]);
  for (int i = t; i < 1048576; i += stride) wqb[i] = cvt4(wq[i]);
  for (int i = t; i < 262144;  i += stride) wkb[i] = cvt4(wk[i]);
  for (int i = t; i < 262144;  i += stride) wvb[i] = cvt4(wv[i]);
  for (int i = t; i < 1048576; i += stride) wob[i] = cvt4(wo[i]);
}

// ---------- QKV projection GEMM ----------
__global__ __launch_bounds__(256) void qkv_gemm(
    const u16* __restrict__ X, const u16* __restrict__ WQ,
    const u16* __restrict__ WK, const u16* __restrict__ WV,
    u16* __restrict__ Qo, u16* __restrict__ Ko, u16* __restrict__ VTo) {
  __shared__ __align__(16) u16 As[128 * 64];
  __shared__ __align__(16) u16 Bs[128 * 64];
  const int tid = threadIdx.x;
  const int l = tid & 63, w = tid >> 6;
  const int wm = w >> 1, wn = w & 1;
  const int bn = blockIdx.x, bm = blockIdx.y;

  const u16* Wsrc;
  int nbase;
  if (bn < 16)      { Wsrc = WQ; nbase = bn * 128; }
  else if (bn < 20) { Wsrc = WK; nbase = bn * 128 - 2048; }
  else              { Wsrc = WV; nbase = bn * 128 - 2560; }

  f32x4 acc[4][4];
#pragma unroll
  for (int i = 0; i < 4; ++i)
#pragma unroll
    for (int j = 0; j < 4; ++j) acc[i][j] = f32x4{0.f, 0.f, 0.f, 0.f};

  const u16* Abase = X + (size_t)bm * 128 * 2048;

  for (int kt = 0; kt < 32; ++kt) {
#pragma unroll
    for (int i = 0; i < 4; ++i) {
      int p = i * 256 + tid;
      int r = p >> 3;
      int c = (p & 7) ^ (r & 7);  // pre-swizzled source column (16B chunks)
      gload_lds16(Abase + (size_t)r * 2048 + kt * 64 + c * 8, As + p * 8);
      gload_lds16(Wsrc + (size_t)(nbase + r) * 2048 + kt * 64 + c * 8, Bs + p * 8);
    }
    __syncthreads();
#pragma unroll
    for (int kk = 0; kk < 2; ++kk) {
      short8 af[4], bfr[4];
#pragma unroll
      for (int mi = 0; mi < 4; ++mi)
        af[mi] = lds_frag(As, wm * 64 + mi * 16 + (l & 15), kk * 4 + (l >> 4));
#pragma unroll
      for (int ni = 0; ni < 4; ++ni)
        bfr[ni] = lds_frag(Bs, wn * 64 + ni * 16 + (l & 15), kk * 4 + (l >> 4));
#pragma unroll
      for (int mi = 0; mi < 4; ++mi)
#pragma unroll
        for (int ni = 0; ni < 4; ++ni)
          acc[mi][ni] = mfma16(af[mi], bfr[ni], acc[mi][ni]);
    }
    __syncthreads();
  }

#pragma unroll
  for (int mi = 0; mi < 4; ++mi) {
    int srow0 = bm * 128 + wm * 64 + mi * 16 + (l >> 4) * 4;
#pragma unroll
    for (int ni = 0; ni < 4; ++ni) {
      int n = nbase + wn * 64 + ni * 16 + (l & 15);
      f32x4 v = acc[mi][ni];
      if (bn < 16) {
#pragma unroll
        for (int r = 0; r < 4; ++r)
          Qo[(size_t)(srow0 + r) * 2048 + n] = f2b(v[r]);
      } else if (bn < 20) {
#pragma unroll
        for (int r = 0; r < 4; ++r)
          Ko[(size_t)(srow0 + r) * 512 + n] = f2b(v[r]);
      } else {
        // V written transposed: VT[d][s]
        ushort4 pk;
        pk.x = f2b(v[0]); pk.y = f2b(v[1]); pk.z = f2b(v[2]); pk.w = f2b(v[3]);
        *(ushort4*)(VTo + (size_t)n * 2048 + srow0) = pk;
      }
    }
  }
}

// ---------- RoPE (in-place; Q scaled by (1/sqrt(64))*log2(e) for exp2 softmax) ----------
__global__ void rope_kernel(u16* __restrict__ Qb, u16* __restrict__ Kb) {
  int idx = blockIdx.x * blockDim.x + threadIdx.x;
  const int NQ = 2048 * 1024;
  const int NT = NQ + 2048 * 256;
  if (idx >= NT) return;
  u16* base;
  int s, p;
  float scale;
  if (idx < NQ) {
    s = idx >> 10; p = idx & 1023;
    base = Qb + (size_t)s * 2048 + p * 2;
    scale = 0.18033688011112042f;  // 0.125 * log2(e)
  } else {
    int j = idx - NQ;
    s = j >> 8; p = j & 255;
    base = Kb + (size_t)s * 512 + p * 2;
    scale = 1.0f;
  }
  int i = p & 31;
  float theta = exp2f(-(float)i * 0.41524101186092034f);
  float ang = (float)s * theta;
  float sn, cs;
  sincosf(ang, &sn, &cs);
  float x0 = b2f(base[0]), x1 = b2f(base[1]);
  u16 o0 = f2b((x0 * cs - x1 * sn) * scale);
  u16 o1 = f2b((x1 * cs + x0 * sn) * scale);
  base[0] = o0;
  base[1] = o1;
}

// ---------- causal flash attention ----------
// grid (64, 8 kv-heads), 256 thr = 4 waves; wave w = q-head kvh*4+w, 32 q-rows.
// Work pairing: qb = (kvh<4) ? 63-x : x, so co-resident blocks (x,y)/(x,y+4)
// have complementary tile counts (sum ~33) -> balanced critical path.
// Swapped QK^T: s = mfma(K,Q) -> lane owns q=l&15 column; softmax reduce =
// in-register + 2 shfl_xor. Defer-max (THR=8, log2 domain) skips O-rescale.
DEVI void stage_kv(const u16* __restrict__ Kb, const u16* __restrict__ VTb,
                   u16* Ksb, u16* Vsb, int kvh, int t, int tid) {
#pragma unroll
  for (int i = 0; i < 2; ++i) {
    int p = i * 256 + tid;
    int r = p >> 3;
    int c = (p & 7) ^ (r & 7);  // pre-swizzled source (16B chunks)
    gload_lds16(Kb + (size_t)(t * 64 + r) * 512 + kvh * 64 + c * 8, Ksb + p * 8);
    gload_lds16(VTb + (size_t)(kvh * 64 + r) * 2048 + t * 64 + c * 8, Vsb + p * 8);
  }
}

__global__ __launch_bounds__(256) void attn_kernel(
    const u16* __restrict__ Qb, const u16* __restrict__ Kb,
    const u16* __restrict__ VTb, u16* __restrict__ AOb) {
  __shared__ __align__(16) u16 Ks[2][64 * 64];
  __shared__ __align__(16) u16 Vs[2][64 * 64];
  __shared__ __align__(16) u16 Ps[4][32 * 64];
  const int tid = threadIdx.x;
  const int l = tid & 63, w = tid >> 6;
  const int kvh = blockIdx.y;
  const int qb = (kvh < 4) ? (63 - (int)blockIdx.x) : (int)blockIdx.x;
  const int h = kvh * 4 + w;
  const int qs = qb * 32;
  const int g = l >> 4;          // lane group 0..3
  const int lc = l & 15;         // lane column 0..15
  u16* pb = &Ps[w][0];

  // Q fragments (B-operand of swapped QK): lane holds Q[q=qs+mi*16+lc][d-range]
  short8 aq[2][2];
#pragma unroll
  for (int mi = 0; mi < 2; ++mi) {
    const u16* qp = Qb + (size_t)(qs + mi * 16 + lc) * 2048 + h * 64 + g * 8;
    aq[mi][0] = *(const short8*)qp;
    aq[mi][1] = *(const short8*)(qp + 32);
  }

  float m[2] = {-1e30f, -1e30f}, ls[2] = {0.f, 0.f};
  f32x4 o[2][4];
#pragma unroll
  for (int mi = 0; mi < 2; ++mi)
#pragma unroll
    for (int dt = 0; dt < 4; ++dt) o[mi][dt] = f32x4{0.f, 0.f, 0.f, 0.f};

  const int nt = (qb >> 1) + 1;

  stage_kv(Kb, VTb, Ks[0], Vs[0], kvh, 0, tid);
  __syncthreads();

  for (int t = 0; t < nt; ++t) {
    const int cur = t & 1;
    if (t + 1 < nt) stage_kv(Kb, VTb, Ks[cur ^ 1], Vs[cur ^ 1], kvh, t + 1, tid);

    // S^T[k][q] = K Q^T : lane holds q=lc, k = ck*16 + g*4 + r
    f32x4 s[2][4];
#pragma unroll
    for (int mi = 0; mi < 2; ++mi)
#pragma unroll
      for (int ck = 0; ck < 4; ++ck) s[mi][ck] = f32x4{0.f, 0.f, 0.f, 0.f};
    __builtin_amdgcn_s_setprio(1);
#pragma unroll
    for (int kk = 0; kk < 2; ++kk)
#pragma unroll
      for (int ck = 0; ck < 4; ++ck) {
        short8 bk = lds_frag(&Ks[cur][0], ck * 16 + lc, kk * 4 + g);
#pragma unroll
        for (int mi = 0; mi < 2; ++mi)
          s[mi][ck] = mfma16(bk, aq[mi][kk], s[mi][ck]);
      }
    __builtin_amdgcn_s_setprio(0);

    // causal mask on the diagonal tile
    if (t == nt - 1) {
#pragma unroll
      for (int mi = 0; mi < 2; ++mi)
#pragma unroll
        for (int ck = 0; ck < 4; ++ck) {
          int kg = t * 64 + ck * 16 + g * 4;
          int qg = qs + mi * 16 + lc;
#pragma unroll
          for (int r = 0; r < 4; ++r)
            if (kg + r > qg) s[mi][ck][r] = -1e30f;
        }
    }

    // tile max per q-column (in-register 16 -> 1, then xor16/xor32)
    float tmax[2];
#pragma unroll
    for (int mi = 0; mi < 2; ++mi) {
      float t0 = s[mi][0][0];
#pragma unroll
      for (int ck = 0; ck < 4; ++ck)
#pragma unroll
        for (int r = 0; r < 4; ++r) t0 = fmaxf(t0, s[mi][ck][r]);
      t0 = fmaxf(t0, __shfl_xor(t0, 16));
      t0 = fmaxf(t0, __shfl_xor(t0, 32));
      tmax[mi] = t0;
    }

    // defer-max: rescale only when some column's max grew past THR=8 (log2)
    if (!__all((tmax[0] <= m[0] + 8.f) && (tmax[1] <= m[1] + 8.f))) {
#pragma unroll
      for (int mi = 0; mi < 2; ++mi) {
        float mn = fmaxf(m[mi], tmax[mi]);
        float al = exp2f(m[mi] - mn);
        m[mi] = mn;
        ls[mi] *= al;
#pragma unroll
        for (int r = 0; r < 4; ++r) {
          float alr = __shfl(al, g * 4 + r);  // col->row layout
#pragma unroll
          for (int dt = 0; dt < 4; ++dt) o[mi][dt][r] *= alr;
        }
      }
    }

    // P = exp2(S - m), row-sum, P -> bf16 -> per-wave LDS (b64 writes)
#pragma unroll
    for (int mi = 0; mi < 2; ++mi) {
      float ps = 0.f;
#pragma unroll
      for (int ck = 0; ck < 4; ++ck) {
#pragma unroll
        for (int r = 0; r < 4; ++r) {
          float e = exp2f(s[mi][ck][r] - m[mi]);
          s[mi][ck][r] = e;
          ps += e;
        }
        int row = mi * 16 + lc;
        int byte = ((row << 7) + ck * 32 + g * 8) ^ ((row & 7) << 4);
        uint2 pk;
        pk.x = pkbf(s[mi][ck][0], s[mi][ck][1]);
        pk.y = pkbf(s[mi][ck][2], s[mi][ck][3]);
        *(uint2*)((char*)pb + byte) = pk;
      }
      ps += __shfl_xor(ps, 16);
      ps += __shfl_xor(ps, 32);
      ls[mi] += ps;
    }

    // O += P V
    __builtin_amdgcn_s_setprio(1);
#pragma unroll
    for (int kk = 0; kk < 2; ++kk) {
      short8 pa[2];
#pragma unroll
      for (int mi = 0; mi < 2; ++mi)
        pa[mi] = lds_frag(pb, mi * 16 + lc, kk * 4 + g);
#pragma unroll
      for (int dt = 0; dt < 4; ++dt) {
        short8 bv = lds_frag(&Vs[cur][0], dt * 16 + lc, kk * 4 + g);
#pragma unroll
        for (int mi = 0; mi < 2; ++mi)
          o[mi][dt] = mfma16(pa[mi], bv, o[mi][dt]);
      }
    }
    __builtin_amdgcn_s_setprio(0);

    __syncthreads();
  }

  // normalize + write (ls converted col->row once)
#pragma unroll
  for (int mi = 0; mi < 2; ++mi)
#pragma unroll
    for (int r = 0; r < 4; ++r) {
      float lsr = __shfl(ls[mi], g * 4 + r);
      float inv = 1.0f / lsr;
#pragma unroll
      for (int dt = 0; dt < 4; ++dt) {
        float v = o[mi][dt][r] * inv;
        AOb[(size_t)(qs + mi * 16 + g * 4 + r) * 2048 + h * 64 + dt * 16 + lc] = f2b(v);
      }
    }
}

// ---------- output projection GEMM (bf16 in, fp32 out) ----------
__global__ __launch_bounds__(256) void out_gemm(
    const u16* __restrict__ A, const u16* __restrict__ W, float* __restrict__ C) {
  __shared__ __align__(16) u16 As[128 * 64];
  __shared__ __align__(16) u16 Bs[128 * 64];
  const int tid = threadIdx.x;
  const int l = tid & 63, w = tid >> 6;
  const int wm = w >> 1, wn = w & 1;
  const int bn = blockIdx.x, bm = blockIdx.y;

  f32x4 acc[4][4];
#pragma unroll
  for (int i = 0; i < 4; ++i)
#pragma unroll
    for (int j = 0; j < 4; ++j) acc[i][j] = f32x4{0.f, 0.f, 0.f, 0.f};

  const u16* Abase = A + (size_t)bm * 128 * 2048;
  const u16* Bbase = W + (size_t)bn * 128 * 2048;

  for (int kt = 0; kt < 32; ++kt) {
#pragma unroll
    for (int i = 0; i < 4; ++i) {
      int p = i * 256 + tid;
      int r = p >> 3;
      int c = (p & 7) ^ (r & 7);
      gload_lds16(Abase + (size_t)r * 2048 + kt * 64 + c * 8, As + p * 8);
      gload_lds16(Bbase + (size_t)r * 2048 + kt * 64 + c * 8, Bs + p * 8);
    }
    __syncthreads();
#pragma unroll
    for (int kk = 0; kk < 2; ++kk) {
      short8 af[4], bfr[4];
#pragma unroll
      for (int mi = 0; mi < 4; ++mi)
        af[mi] = lds_frag(As, wm * 64 + mi * 16 + (l & 15), kk * 4 + (l >> 4));
#pragma unroll
      for (int ni = 0; ni < 4; ++ni)
        bfr[ni] = lds_frag(Bs, wn * 64 + ni * 16 + (l & 15), kk * 4 + (l >> 4));
#pragma unroll
      for (int mi = 0; mi < 4; ++mi)
#pragma unroll
        for (int ni = 0; ni < 4; ++ni)
          acc[mi][ni] = mfma16(af[mi], bfr[ni], acc[mi][ni]);
    }
    __syncthreads();
  }

#pragma unroll
  for (int mi = 0; mi < 4; ++mi) {
    int srow0 = bm * 128 + wm * 64 + mi * 16 + (l >> 4) * 4;
#pragma unroll
    for (int ni = 0; ni < 4; ++ni) {
      int n = bn * 128 + wn * 64 + ni * 16 + (l & 15);
#pragma unroll
      for (int r = 0; r < 4; ++r)
        C[(size_t)(srow0 + r) * 2048 + n] = acc[mi][ni][r];
    }
  }
}

// ---------- launch ----------
extern "C" void kernel_launch(void* const* d_in, const int* in_sizes, int n_in,
                              void* d_out, int out_size, void* d_ws, size_t ws_size,
                              hipStream_t stream) {
  (void)in_sizes; (void)n_in; (void)out_size; (void)ws_size;
  const float* x  = (const float*)d_in[0];
  const float* wq = (const float*)d_in[1];
  const float* wk = (const float*)d_in[2];
  const float* wv = (const float*)d_in[3];
  const float* wo = (const float*)d_in[4];
  float* out = (float*)d_out;
  char* ws = (char*)d_ws;

  u16* xbf  = (u16*)(ws + 0);
  u16* wqbf = (u16*)(ws + 8388608);
  u16* wkbf = (u16*)(ws + 16777216);
  u16* wvbf = (u16*)(ws + 18874368);
  u16* wobf = (u16*)(ws + 20971520);
  u16* Qb   = (u16*)(ws + 29360128);
  u16* Kb   = (u16*)(ws + 37748736);
  u16* VTb  = (u16*)(ws + 39845888);
  u16* AOb  = (u16*)(ws + 41943040);

  cvt_kernel<<<2048, 256, 0, stream>>>(
      (const float4*)x, (const float4*)wq, (const float4*)wk,
      (const float4*)wv, (const float4*)wo,
      (ushort4*)xbf, (ushort4*)wqbf, (ushort4*)wkbf, (ushort4*)wvbf, (ushort4*)wobf);

  qkv_gemm<<<dim3(24, 16), 256, 0, stream>>>(xbf, wqbf, wkbf, wvbf, Qb, Kb, VTb);

  rope_kernel<<<(2048 * 1024 + 2048 * 256 + 255) / 256, 256, 0, stream>>>(Qb, Kb);

  attn_kernel<<<dim3(64, 8), 256, 0, stream>>>(Qb, Kb, VTb, AOb);

  out_gemm<<<dim3(16, 16), 256, 0, stream>>>(AOb, wobf, out);
}

// Round 5
// 167.024 us; speedup vs baseline: 1.3061x; 1.0182x over previous
//
#include <hip/hip_runtime.h>
#include <hip/hip_bf16.h>
#include <stdint.h>

#define DEVI __device__ __forceinline__

typedef unsigned short u16;
typedef __attribute__((ext_vector_type(8))) short short8;
typedef __attribute__((ext_vector_type(8))) __bf16 bf16x8;
typedef __attribute__((ext_vector_type(4))) float f32x4;
typedef __attribute__((ext_vector_type(4))) uint32_t u32x4;

// ---------- small helpers ----------
DEVI u16 f2b(float f) {
  __hip_bfloat16 h = __float2bfloat16(f);
  return __builtin_bit_cast(u16, h);
}
DEVI float b2f(u16 u) {
  union { float f; uint32_t i; } v;
  v.i = ((uint32_t)u) << 16;
  return v.f;
}

DEVI f32x4 mfma16(short8 a, short8 b, f32x4 c) {
  return __builtin_amdgcn_mfma_f32_16x16x32_bf16(
      __builtin_bit_cast(bf16x8, a), __builtin_bit_cast(bf16x8, b), c, 0, 0, 0);
}

// async global->LDS, 16B per lane; LDS dest = wave-uniform base + lane*16
DEVI void gload_lds16(const u16* g, u16* l) {
  __builtin_amdgcn_global_load_lds(
      (const __attribute__((address_space(1))) uint32_t*)g,
      (__attribute__((address_space(3))) uint32_t*)l, 16, 0, 0);
}

// Swizzled ds_read_b128 of an MFMA fragment from a [rows][64] bf16 tile
DEVI short8 lds_frag(const u16* base, int row, int col16) {
  int byte = (row << 7) ^ (col16 << 4) ^ ((row & 7) << 4);
  return *(const short8*)((const char*)base + byte);
}

// v_cvt_pk_bf16_f32: dst.lo = bf16(lo), dst.hi = bf16(hi)
DEVI uint32_t cvtpk(float lo, float hi) {
  uint32_t r;
  asm("v_cvt_pk_bf16_f32 %0, %1, %2" : "=v"(r) : "v"(lo), "v"(hi));
  return r;
}
// a' = {a.r0,a.r1,b.r0,b.r1}; b' = {a.r2,a.r3,b.r2,b.r3} (rows of 16 lanes)
// NOTE: operands must hold DISTINCT values (same-value operands can be
// register-coalesced by the compiler -> self-swap -> silent corruption;
// that was the round-4 bug in the reductions).
DEVI void swap32(uint32_t& a, uint32_t& b) {
  asm("v_permlane32_swap_b32 %0, %1" : "+v"(a), "+v"(b));
}
// a' = {a.r0,b.r0,a.r2,b.r2}; b' = {a.r1,b.r1,a.r3,b.r3}
DEVI void swap16(uint32_t& a, uint32_t& b) {
  asm("v_permlane16_swap_b32 %0, %1" : "+v"(a), "+v"(b));
}

// ---------- fp32 -> bf16 conversion of inputs ----------
DEVI ushort4 cvt4(float4 v) {
  ushort4 o;
  o.x = f2b(v.x); o.y = f2b(v.y); o.z = f2b(v.z); o.w = f2b(v.w);
  return o;
}

__global__ void cvt_kernel(const float4* __restrict__ x, const float4* __restrict__ wq,
                           const float4* __restrict__ wk, const float4* __restrict__ wv,
                           const float4* __restrict__ wo,
                           ushort4* __restrict__ xb, ushort4* __restrict__ wqb,
                           ushort4* __restrict__ wkb, ushort4* __restrict__ wvb,
                           ushort4* __restrict__ wob) {
  int t = blockIdx.x * blockDim.x + threadIdx.x;
  int stride = gridDim.x * blockDim.x;
  for (int i = t; i < 1048576; i += stride) xb[i]  = cvt4(x[i]);
  for (int i = t; i < 1048576; i += stride) wqb[i] = cvt4(wq[i]);
  for (int i = t; i < 262144;  i += stride) wkb[i] = cvt4(wk[i]);
  for (int i = t; i < 262144;  i += stride) wvb[i] = cvt4(wv[i]);
  for (int i = t; i < 1048576; i += stride) wob[i] = cvt4(wo[i]);
}

// ---------- QKV projection GEMM ----------
__global__ __launch_bounds__(256) void qkv_gemm(
    const u16* __restrict__ X, const u16* __restrict__ WQ,
    const u16* __restrict__ WK, const u16* __restrict__ WV,
    u16* __restrict__ Qo, u16* __restrict__ Ko, u16* __restrict__ VTo) {
  __shared__ __align__(16) u16 As[128 * 64];
  __shared__ __align__(16) u16 Bs[128 * 64];
  const int tid = threadIdx.x;
  const int l = tid & 63, w = tid >> 6;
  const int wm = w >> 1, wn = w & 1;
  const int bn = blockIdx.x, bm = blockIdx.y;

  const u16* Wsrc;
  int nbase;
  if (bn < 16)      { Wsrc = WQ; nbase = bn * 128; }
  else if (bn < 20) { Wsrc = WK; nbase = bn * 128 - 2048; }
  else              { Wsrc = WV; nbase = bn * 128 - 2560; }

  f32x4 acc[4][4];
#pragma unroll
  for (int i = 0; i < 4; ++i)
#pragma unroll
    for (int j = 0; j < 4; ++j) acc[i][j] = f32x4{0.f, 0.f, 0.f, 0.f};

  const u16* Abase = X + (size_t)bm * 128 * 2048;

  for (int kt = 0; kt < 32; ++kt) {
#pragma unroll
    for (int i = 0; i < 4; ++i) {
      int p = i * 256 + tid;
      int r = p >> 3;
      int c = (p & 7) ^ (r & 7);
      gload_lds16(Abase + (size_t)r * 2048 + kt * 64 + c * 8, As + p * 8);
      gload_lds16(Wsrc + (size_t)(nbase + r) * 2048 + kt * 64 + c * 8, Bs + p * 8);
    }
    __syncthreads();
#pragma unroll
    for (int kk = 0; kk < 2; ++kk) {
      short8 af[4], bfr[4];
#pragma unroll
      for (int mi = 0; mi < 4; ++mi)
        af[mi] = lds_frag(As, wm * 64 + mi * 16 + (l & 15), kk * 4 + (l >> 4));
#pragma unroll
      for (int ni = 0; ni < 4; ++ni)
        bfr[ni] = lds_frag(Bs, wn * 64 + ni * 16 + (l & 15), kk * 4 + (l >> 4));
#pragma unroll
      for (int mi = 0; mi < 4; ++mi)
#pragma unroll
        for (int ni = 0; ni < 4; ++ni)
          acc[mi][ni] = mfma16(af[mi], bfr[ni], acc[mi][ni]);
    }
    __syncthreads();
  }

#pragma unroll
  for (int mi = 0; mi < 4; ++mi) {
    int srow0 = bm * 128 + wm * 64 + mi * 16 + (l >> 4) * 4;
#pragma unroll
    for (int ni = 0; ni < 4; ++ni) {
      int n = nbase + wn * 64 + ni * 16 + (l & 15);
      f32x4 v = acc[mi][ni];
      if (bn < 16) {
#pragma unroll
        for (int r = 0; r < 4; ++r)
          Qo[(size_t)(srow0 + r) * 2048 + n] = f2b(v[r]);
      } else if (bn < 20) {
#pragma unroll
        for (int r = 0; r < 4; ++r)
          Ko[(size_t)(srow0 + r) * 512 + n] = f2b(v[r]);
      } else {
        ushort4 pk;
        pk.x = f2b(v[0]); pk.y = f2b(v[1]); pk.z = f2b(v[2]); pk.w = f2b(v[3]);
        *(ushort4*)(VTo + (size_t)n * 2048 + srow0) = pk;
      }
    }
  }
}

// ---------- RoPE (in-place; Q scaled by (1/sqrt(64))*log2(e) for exp2 softmax) ----------
__global__ void rope_kernel(u16* __restrict__ Qb, u16* __restrict__ Kb) {
  int idx = blockIdx.x * blockDim.x + threadIdx.x;
  const int NQ = 2048 * 1024;
  const int NT = NQ + 2048 * 256;
  if (idx >= NT) return;
  u16* base;
  int s, p;
  float scale;
  if (idx < NQ) {
    s = idx >> 10; p = idx & 1023;
    base = Qb + (size_t)s * 2048 + p * 2;
    scale = 0.18033688011112042f;  // 0.125 * log2(e)
  } else {
    int j = idx - NQ;
    s = j >> 8; p = j & 255;
    base = Kb + (size_t)s * 512 + p * 2;
    scale = 1.0f;
  }
  int i = p & 31;
  float theta = exp2f(-(float)i * 0.41524101186092034f);
  float ang = (float)s * theta;
  float sn, cs;
  sincosf(ang, &sn, &cs);
  float x0 = b2f(base[0]), x1 = b2f(base[1]);
  u16 o0 = f2b((x0 * cs - x1 * sn) * scale);
  u16 o1 = f2b((x1 * cs + x0 * sn) * scale);
  base[0] = o0;
  base[1] = o1;
}

// ---------- causal flash attention ----------
// grid (64, 8 kv-heads), 4 waves; wave w = q-head kvh*4+w, 32 q-rows.
// Complementary pairing balances per-CU tile counts.
// Swapped QK^T: lane (g,lc) holds P[q=lc][k=16ck+4g+r]. P->PV A-frags built
// fully in-register via cvt_pk + permlane{32,16}_swap (T12): no P LDS trip.
// Reductions across the 4 lane-groups use verified __shfl_xor(16/32).
DEVI void stage_kv(const u16* __restrict__ Kb, const u16* __restrict__ VTb,
                   u16* Ksb, u16* Vsb, int kvh, int t, int tid) {
#pragma unroll
  for (int i = 0; i < 2; ++i) {
    int p = i * 256 + tid;
    int r = p >> 3;
    int c = (p & 7) ^ (r & 7);
    gload_lds16(Kb + (size_t)(t * 64 + r) * 512 + kvh * 64 + c * 8, Ksb + p * 8);
    gload_lds16(VTb + (size_t)(kvh * 64 + r) * 2048 + t * 64 + c * 8, Vsb + p * 8);
  }
}

__global__ __launch_bounds__(256) void attn_kernel(
    const u16* __restrict__ Qb, const u16* __restrict__ Kb,
    const u16* __restrict__ VTb, u16* __restrict__ AOb) {
  __shared__ __align__(16) u16 Ks[2][64 * 64];
  __shared__ __align__(16) u16 Vs[2][64 * 64];
  const int tid = threadIdx.x;
  const int l = tid & 63, w = tid >> 6;
  const int kvh = blockIdx.y;
  const int qb = (kvh < 4) ? (63 - (int)blockIdx.x) : (int)blockIdx.x;
  const int h = kvh * 4 + w;
  const int qs = qb * 32;
  const int g = l >> 4;          // lane group 0..3
  const int lc = l & 15;         // lane column 0..15

  // Q fragments (B-operand of swapped QK)
  short8 aq[2][2];
#pragma unroll
  for (int mi = 0; mi < 2; ++mi) {
    const u16* qp = Qb + (size_t)(qs + mi * 16 + lc) * 2048 + h * 64 + g * 8;
    aq[mi][0] = *(const short8*)qp;
    aq[mi][1] = *(const short8*)(qp + 32);
  }

  float m[2] = {-1e30f, -1e30f}, ls[2] = {0.f, 0.f};
  f32x4 o[2][4];
#pragma unroll
  for (int mi = 0; mi < 2; ++mi)
#pragma unroll
    for (int dt = 0; dt < 4; ++dt) o[mi][dt] = f32x4{0.f, 0.f, 0.f, 0.f};

  const int nt = (qb >> 1) + 1;

  stage_kv(Kb, VTb, Ks[0], Vs[0], kvh, 0, tid);
  __syncthreads();

  for (int t = 0; t < nt; ++t) {
    const int cur = t & 1;
    if (t + 1 < nt) stage_kv(Kb, VTb, Ks[cur ^ 1], Vs[cur ^ 1], kvh, t + 1, tid);

    // S^T[k][q] = K Q^T : lane (g,lc) holds q=lc, k = ck*16 + g*4 + r
    f32x4 s[2][4];
#pragma unroll
    for (int mi = 0; mi < 2; ++mi)
#pragma unroll
      for (int ck = 0; ck < 4; ++ck) s[mi][ck] = f32x4{0.f, 0.f, 0.f, 0.f};
    __builtin_amdgcn_s_setprio(1);
#pragma unroll
    for (int kk = 0; kk < 2; ++kk)
#pragma unroll
      for (int ck = 0; ck < 4; ++ck) {
        short8 bk = lds_frag(&Ks[cur][0], ck * 16 + lc, kk * 4 + g);
#pragma unroll
        for (int mi = 0; mi < 2; ++mi)
          s[mi][ck] = mfma16(bk, aq[mi][kk], s[mi][ck]);
      }
    __builtin_amdgcn_s_setprio(0);

    // causal mask on the diagonal tile
    if (t == nt - 1) {
#pragma unroll
      for (int mi = 0; mi < 2; ++mi)
#pragma unroll
        for (int ck = 0; ck < 4; ++ck) {
          int kg = t * 64 + ck * 16 + g * 4;
          int qg = qs + mi * 16 + lc;
#pragma unroll
          for (int r = 0; r < 4; ++r)
            if (kg + r > qg) s[mi][ck][r] = -1e30f;
        }
    }

    // tile max per q-column (in-register 16 -> 1, then verified shfl reduce)
    float tmax[2];
#pragma unroll
    for (int mi = 0; mi < 2; ++mi) {
      float t0 = s[mi][0][0];
#pragma unroll
      for (int ck = 0; ck < 4; ++ck)
#pragma unroll
        for (int r = 0; r < 4; ++r) t0 = fmaxf(t0, s[mi][ck][r]);
      t0 = fmaxf(t0, __shfl_xor(t0, 16));
      t0 = fmaxf(t0, __shfl_xor(t0, 32));
      tmax[mi] = t0;
    }

    // defer-max: rescale only when some column's max grew past THR=8 (log2)
    if (!__all((tmax[0] <= m[0] + 8.f) && (tmax[1] <= m[1] + 8.f))) {
#pragma unroll
      for (int mi = 0; mi < 2; ++mi) {
        float mn = fmaxf(m[mi], tmax[mi]);
        float al = exp2f(m[mi] - mn);
        m[mi] = mn;
        ls[mi] *= al;
#pragma unroll
        for (int r = 0; r < 4; ++r) {
          float alr = __shfl(al, g * 4 + r);  // col->row layout
#pragma unroll
          for (int dt = 0; dt < 4; ++dt) o[mi][dt][r] *= alr;
        }
      }
    }

    // P = exp2(S - m); row-sum; pack to PV A-fragments fully in-register.
    // pfrag[mi][kk] lane (g,lc) = P[q=lc][32kk + 8g + 0..7]
    short8 pfrag[2][2];
#pragma unroll
    for (int mi = 0; mi < 2; ++mi) {
      float ps = 0.f;
      uint32_t d0[4], d1[4];
#pragma unroll
      for (int ck = 0; ck < 4; ++ck) {
        float e0 = exp2f(s[mi][ck][0] - m[mi]);
        float e1 = exp2f(s[mi][ck][1] - m[mi]);
        float e2 = exp2f(s[mi][ck][2] - m[mi]);
        float e3 = exp2f(s[mi][ck][3] - m[mi]);
        ps += (e0 + e1) + (e2 + e3);
        d0[ck] = cvtpk(e0, e1);
        d1[ck] = cvtpk(e2, e3);
      }
      ps += __shfl_xor(ps, 16);
      ps += __shfl_xor(ps, 32);
      ls[mi] += ps;
#pragma unroll
      for (int kk = 0; kk < 2; ++kk) {
        uint32_t A0 = d0[2 * kk], B0 = d0[2 * kk + 1];
        swap32(A0, B0); swap16(A0, B0);   // A0 = dw0, B0 = dw2
        uint32_t A1 = d1[2 * kk], B1 = d1[2 * kk + 1];
        swap32(A1, B1); swap16(A1, B1);   // A1 = dw1, B1 = dw3
        u32x4 u = {A0, A1, B0, B1};
        pfrag[mi][kk] = __builtin_bit_cast(short8, u);
      }
    }

    // O += P V
    __builtin_amdgcn_s_setprio(1);
#pragma unroll
    for (int kk = 0; kk < 2; ++kk)
#pragma unroll
      for (int dt = 0; dt < 4; ++dt) {
        short8 bv = lds_frag(&Vs[cur][0], dt * 16 + lc, kk * 4 + g);
#pragma unroll
        for (int mi = 0; mi < 2; ++mi)
          o[mi][dt] = mfma16(pfrag[mi][kk], bv, o[mi][dt]);
      }
    __builtin_amdgcn_s_setprio(0);

    __syncthreads();
  }

  // normalize + write (ls converted col->row once)
#pragma unroll
  for (int mi = 0; mi < 2; ++mi)
#pragma unroll
    for (int r = 0; r < 4; ++r) {
      float lsr = __shfl(ls[mi], g * 4 + r);
      float inv = 1.0f / lsr;
#pragma unroll
      for (int dt = 0; dt < 4; ++dt) {
        float v = o[mi][dt][r] * inv;
        AOb[(size_t)(qs + mi * 16 + g * 4 + r) * 2048 + h * 64 + dt * 16 + lc] = f2b(v);
      }
    }
}

// ---------- output projection GEMM (bf16 in, fp32 out) ----------
__global__ __launch_bounds__(256) void out_gemm(
    const u16* __restrict__ A, const u16* __restrict__ W, float* __restrict__ C) {
  __shared__ __align__(16) u16 As[128 * 64];
  __shared__ __align__(16) u16 Bs[128 * 64];
  const int tid = threadIdx.x;
  const int l = tid & 63, w = tid >> 6;
  const int wm = w >> 1, wn = w & 1;
  const int bn = blockIdx.x, bm = blockIdx.y;

  f32x4 acc[4][4];
#pragma unroll
  for (int i = 0; i < 4; ++i)
#pragma unroll
    for (int j = 0; j < 4; ++j) acc[i][j] = f32x4{0.f, 0.f, 0.f, 0.f};

  const u16* Abase = A + (size_t)bm * 128 * 2048;
  const u16* Bbase = W + (size_t)bn * 128 * 2048;

  for (int kt = 0; kt < 32; ++kt) {
#pragma unroll
    for (int i = 0; i < 4; ++i) {
      int p = i * 256 + tid;
      int r = p >> 3;
      int c = (p & 7) ^ (r & 7);
      gload_lds16(Abase + (size_t)r * 2048 + kt * 64 + c * 8, As + p * 8);
      gload_lds16(Bbase + (size_t)r * 2048 + kt * 64 + c * 8, Bs + p * 8);
    }
    __syncthreads();
#pragma unroll
    for (int kk = 0; kk < 2; ++kk) {
      short8 af[4], bfr[4];
#pragma unroll
      for (int mi = 0; mi < 4; ++mi)
        af[mi] = lds_frag(As, wm * 64 + mi * 16 + (l & 15), kk * 4 + (l >> 4));
#pragma unroll
      for (int ni = 0; ni < 4; ++ni)
        bfr[ni] = lds_frag(Bs, wn * 64 + ni * 16 + (l & 15), kk * 4 + (l >> 4));
#pragma unroll
      for (int mi = 0; mi < 4; ++mi)
#pragma unroll
        for (int ni = 0; ni < 4; ++ni)
          acc[mi][ni] = mfma16(af[mi], bfr[ni], acc[mi][ni]);
    }
    __syncthreads();
  }

#pragma unroll
  for (int mi = 0; mi < 4; ++mi) {
    int srow0 = bm * 128 + wm * 64 + mi * 16 + (l >> 4) * 4;
#pragma unroll
    for (int ni = 0; ni < 4; ++ni) {
      int n = bn * 128 + wn * 64 + ni * 16 + (l & 15);
#pragma unroll
      for (int r = 0; r < 4; ++r)
        C[(size_t)(srow0 + r) * 2048 + n] = acc[mi][ni][r];
    }
  }
}

// ---------- launch ----------
extern "C" void kernel_launch(void* const* d_in, const int* in_sizes, int n_in,
                              void* d_out, int out_size, void* d_ws, size_t ws_size,
                              hipStream_t stream) {
  (void)in_sizes; (void)n_in; (void)out_size; (void)ws_size;
  const float* x  = (const float*)d_in[0];
  const float* wq = (const float*)d_in[1];
  const float* wk = (const float*)d_in[2];
  const float* wv = (const float*)d_in[3];
  const float* wo = (const float*)d_in[4];
  float* out = (float*)d_out;
  char* ws = (char*)d_ws;

  u16* xbf  = (u16*)(ws + 0);
  u16* wqbf = (u16*)(ws + 8388608);
  u16* wkbf = (u16*)(ws + 16777216);
  u16* wvbf = (u16*)(ws + 18874368);
  u16* wobf = (u16*)(ws + 20971520);
  u16* Qb   = (u16*)(ws + 29360128);
  u16* Kb   = (u16*)(ws + 37748736);
  u16* VTb  = (u16*)(ws + 39845888);
  u16* AOb  = (u16*)(ws + 41943040);

  cvt_kernel<<<2048, 256, 0, stream>>>(
      (const float4*)x, (const float4*)wq, (const float4*)wk,
      (const float4*)wv, (const float4*)wo,
      (ushort4*)xbf, (ushort4*)wqbf, (ushort4*)wkbf, (ushort4*)wvbf, (ushort4*)wobf);

  qkv_gemm<<<dim3(24, 16), 256, 0, stream>>>(xbf, wqbf, wkbf, wvbf, Qb, Kb, VTb);

  rope_kernel<<<(2048 * 1024 + 2048 * 256 + 255) / 256, 256, 0, stream>>>(Qb, Kb);

  attn_kernel<<<dim3(64, 8), 256, 0, stream>>>(Qb, Kb, VTb, AOb);

  out_gemm<<<dim3(16, 16), 256, 0, stream>>>(AOb, wobf, out);
}

// Round 6
// 158.168 us; speedup vs baseline: 1.3793x; 1.0560x over previous
//
#include <hip/hip_runtime.h>
#include <hip/hip_bf16.h>
#include <stdint.h>

#define DEVI __device__ __forceinline__

typedef unsigned short u16;
typedef __attribute__((ext_vector_type(8))) short short8;
typedef __attribute__((ext_vector_type(8))) __bf16 bf16x8;
typedef __attribute__((ext_vector_type(4))) float f32x4;
typedef __attribute__((ext_vector_type(4))) uint32_t u32x4;

// ---------- small helpers ----------
DEVI u16 f2b(float f) {
  __hip_bfloat16 h = __float2bfloat16(f);
  return __builtin_bit_cast(u16, h);
}
DEVI float b2f(u16 u) {
  union { float f; uint32_t i; } v;
  v.i = ((uint32_t)u) << 16;
  return v.f;
}

DEVI f32x4 mfma16(short8 a, short8 b, f32x4 c) {
  return __builtin_amdgcn_mfma_f32_16x16x32_bf16(
      __builtin_bit_cast(bf16x8, a), __builtin_bit_cast(bf16x8, b), c, 0, 0, 0);
}

// async global->LDS, 16B per lane; LDS dest = wave-uniform base + lane*16
DEVI void gload_lds16(const u16* g, u16* l) {
  __builtin_amdgcn_global_load_lds(
      (const __attribute__((address_space(1))) uint32_t*)g,
      (__attribute__((address_space(3))) uint32_t*)l, 16, 0, 0);
}

// Swizzled ds_read_b128 of an MFMA fragment from a [rows][64] bf16 tile
DEVI short8 lds_frag(const u16* base, int row, int col16) {
  int byte = (row << 7) ^ (col16 << 4) ^ ((row & 7) << 4);
  return *(const short8*)((const char*)base + byte);
}

// v_cvt_pk_bf16_f32: dst.lo = bf16(lo), dst.hi = bf16(hi)
DEVI uint32_t cvtpk(float lo, float hi) {
  uint32_t r;
  asm("v_cvt_pk_bf16_f32 %0, %1, %2" : "=v"(r) : "v"(lo), "v"(hi));
  return r;
}
// a' = {a.r0,a.r1,b.r0,b.r1}; b' = {a.r2,a.r3,b.r2,b.r3} (rows of 16 lanes)
// NOTE: operands must hold DISTINCT values (same-value operands get
// register-coalesced -> self-swap -> silent corruption; round-4 bug).
DEVI void swap32(uint32_t& a, uint32_t& b) {
  asm("v_permlane32_swap_b32 %0, %1" : "+v"(a), "+v"(b));
}
// a' = {a.r0,b.r0,a.r2,b.r2}; b' = {a.r1,b.r1,a.r3,b.r3}
DEVI void swap16(uint32_t& a, uint32_t& b) {
  asm("v_permlane16_swap_b32 %0, %1" : "+v"(a), "+v"(b));
}

// ---------- fp32 -> bf16 conversion of inputs ----------
DEVI ushort4 cvt4(float4 v) {
  ushort4 o;
  o.x = f2b(v.x); o.y = f2b(v.y); o.z = f2b(v.z); o.w = f2b(v.w);
  return o;
}

__global__ void cvt_kernel(const float4* __restrict__ x, const float4* __restrict__ wq,
                           const float4* __restrict__ wk, const float4* __restrict__ wv,
                           const float4* __restrict__ wo,
                           ushort4* __restrict__ xb, ushort4* __restrict__ wqb,
                           ushort4* __restrict__ wkb, ushort4* __restrict__ wvb,
                           ushort4* __restrict__ wob) {
  int t = blockIdx.x * blockDim.x + threadIdx.x;
  int stride = gridDim.x * blockDim.x;
  for (int i = t; i < 1048576; i += stride) xb[i]  = cvt4(x[i]);
  for (int i = t; i < 1048576; i += stride) wqb[i] = cvt4(wq[i]);
  for (int i = t; i < 262144;  i += stride) wkb[i] = cvt4(wk[i]);
  for (int i = t; i < 262144;  i += stride) wvb[i] = cvt4(wv[i]);
  for (int i = t; i < 1048576; i += stride) wob[i] = cvt4(wo[i]);
}

// ---------- QKV projection GEMM ----------
__global__ __launch_bounds__(256) void qkv_gemm(
    const u16* __restrict__ X, const u16* __restrict__ WQ,
    const u16* __restrict__ WK, const u16* __restrict__ WV,
    u16* __restrict__ Qo, u16* __restrict__ Ko, u16* __restrict__ VTo) {
  __shared__ __align__(16) u16 As[128 * 64];
  __shared__ __align__(16) u16 Bs[128 * 64];
  const int tid = threadIdx.x;
  const int l = tid & 63, w = tid >> 6;
  const int wm = w >> 1, wn = w & 1;
  const int bn = blockIdx.x, bm = blockIdx.y;

  const u16* Wsrc;
  int nbase;
  if (bn < 16)      { Wsrc = WQ; nbase = bn * 128; }
  else if (bn < 20) { Wsrc = WK; nbase = bn * 128 - 2048; }
  else              { Wsrc = WV; nbase = bn * 128 - 2560; }

  f32x4 acc[4][4];
#pragma unroll
  for (int i = 0; i < 4; ++i)
#pragma unroll
    for (int j = 0; j < 4; ++j) acc[i][j] = f32x4{0.f, 0.f, 0.f, 0.f};

  const u16* Abase = X + (size_t)bm * 128 * 2048;

  for (int kt = 0; kt < 32; ++kt) {
#pragma unroll
    for (int i = 0; i < 4; ++i) {
      int p = i * 256 + tid;
      int r = p >> 3;
      int c = (p & 7) ^ (r & 7);
      gload_lds16(Abase + (size_t)r * 2048 + kt * 64 + c * 8, As + p * 8);
      gload_lds16(Wsrc + (size_t)(nbase + r) * 2048 + kt * 64 + c * 8, Bs + p * 8);
    }
    __syncthreads();
#pragma unroll
    for (int kk = 0; kk < 2; ++kk) {
      short8 af[4], bfr[4];
#pragma unroll
      for (int mi = 0; mi < 4; ++mi)
        af[mi] = lds_frag(As, wm * 64 + mi * 16 + (l & 15), kk * 4 + (l >> 4));
#pragma unroll
      for (int ni = 0; ni < 4; ++ni)
        bfr[ni] = lds_frag(Bs, wn * 64 + ni * 16 + (l & 15), kk * 4 + (l >> 4));
#pragma unroll
      for (int mi = 0; mi < 4; ++mi)
#pragma unroll
        for (int ni = 0; ni < 4; ++ni)
          acc[mi][ni] = mfma16(af[mi], bfr[ni], acc[mi][ni]);
    }
    __syncthreads();
  }

#pragma unroll
  for (int mi = 0; mi < 4; ++mi) {
    int srow0 = bm * 128 + wm * 64 + mi * 16 + (l >> 4) * 4;
#pragma unroll
    for (int ni = 0; ni < 4; ++ni) {
      int n = nbase + wn * 64 + ni * 16 + (l & 15);
      f32x4 v = acc[mi][ni];
      if (bn < 16) {
#pragma unroll
        for (int r = 0; r < 4; ++r)
          Qo[(size_t)(srow0 + r) * 2048 + n] = f2b(v[r]);
      } else if (bn < 20) {
#pragma unroll
        for (int r = 0; r < 4; ++r)
          Ko[(size_t)(srow0 + r) * 512 + n] = f2b(v[r]);
      } else {
        ushort4 pk;
        pk.x = f2b(v[0]); pk.y = f2b(v[1]); pk.z = f2b(v[2]); pk.w = f2b(v[3]);
        *(ushort4*)(VTo + (size_t)n * 2048 + srow0) = pk;
      }
    }
  }
}

// ---------- RoPE (in-place; Q scaled by (1/sqrt(64))*log2(e) for exp2 softmax) ----------
__global__ void rope_kernel(u16* __restrict__ Qb, u16* __restrict__ Kb) {
  int idx = blockIdx.x * blockDim.x + threadIdx.x;
  const int NQ = 2048 * 1024;
  const int NT = NQ + 2048 * 256;
  if (idx >= NT) return;
  u16* base;
  int s, p;
  float scale;
  if (idx < NQ) {
    s = idx >> 10; p = idx & 1023;
    base = Qb + (size_t)s * 2048 + p * 2;
    scale = 0.18033688011112042f;  // 0.125 * log2(e)
  } else {
    int j = idx - NQ;
    s = j >> 8; p = j & 255;
    base = Kb + (size_t)s * 512 + p * 2;
    scale = 1.0f;
  }
  int i = p & 31;
  float theta = exp2f(-(float)i * 0.41524101186092034f);
  float ang = (float)s * theta;
  float sn, cs;
  sincosf(ang, &sn, &cs);
  float x0 = b2f(base[0]), x1 = b2f(base[1]);
  u16 o0 = f2b((x0 * cs - x1 * sn) * scale);
  u16 o1 = f2b((x1 * cs + x0 * sn) * scale);
  base[0] = o0;
  base[1] = o1;
}

// ---------- causal flash attention ----------
// grid (128, 8 kv-heads), 4 waves; wave w = q-head kvh*4+w, 16 q-rows each.
// QBLK=16 -> 1024 blocks = 4 blocks/CU = 4 waves/SIMD (TLP hides the
// per-tile softmax/MFMA latency chain; round-5 had only 2 waves/SIMD).
// Complementary pairing: ids of (x,kvh) and (x,kvh+4) differ by 512 = 0 mod
// 256 -> co-resident blocks have nt summing to ~33.
// Swapped QK^T: lane (g,lc) holds P[q=lc][k=16ck+4g+r]. P->PV A-frags built
// fully in-register via cvt_pk + permlane{32,16}_swap (T12): no P LDS trip.
DEVI void stage_kv(const u16* __restrict__ Kb, const u16* __restrict__ VTb,
                   u16* Ksb, u16* Vsb, int kvh, int t, int tid) {
#pragma unroll
  for (int i = 0; i < 2; ++i) {
    int p = i * 256 + tid;
    int r = p >> 3;
    int c = (p & 7) ^ (r & 7);
    gload_lds16(Kb + (size_t)(t * 64 + r) * 512 + kvh * 64 + c * 8, Ksb + p * 8);
    gload_lds16(VTb + (size_t)(kvh * 64 + r) * 2048 + t * 64 + c * 8, Vsb + p * 8);
  }
}

__global__ __launch_bounds__(256) void attn_kernel(
    const u16* __restrict__ Qb, const u16* __restrict__ Kb,
    const u16* __restrict__ VTb, u16* __restrict__ AOb) {
  __shared__ __align__(16) u16 Ks[2][64 * 64];
  __shared__ __align__(16) u16 Vs[2][64 * 64];
  const int tid = threadIdx.x;
  const int l = tid & 63, w = tid >> 6;
  const int kvh = blockIdx.y;
  const int qb = (kvh < 4) ? (127 - (int)blockIdx.x) : (int)blockIdx.x;
  const int h = kvh * 4 + w;
  const int qs = qb * 16;
  const int g = l >> 4;          // lane group 0..3
  const int lc = l & 15;         // lane column 0..15

  // Q fragments (B-operand of swapped QK): lane holds Q[q=qs+lc][d-range]
  short8 aq[2];
  {
    const u16* qp = Qb + (size_t)(qs + lc) * 2048 + h * 64 + g * 8;
    aq[0] = *(const short8*)qp;
    aq[1] = *(const short8*)(qp + 32);
  }

  float m = -1e30f, ls = 0.f;
  f32x4 o[4];
#pragma unroll
  for (int dt = 0; dt < 4; ++dt) o[dt] = f32x4{0.f, 0.f, 0.f, 0.f};

  const int nt = (qb >> 2) + 1;

  stage_kv(Kb, VTb, Ks[0], Vs[0], kvh, 0, tid);
  __syncthreads();

  for (int t = 0; t < nt; ++t) {
    const int cur = t & 1;
    if (t + 1 < nt) stage_kv(Kb, VTb, Ks[cur ^ 1], Vs[cur ^ 1], kvh, t + 1, tid);

    // S^T[k][q] = K Q^T : lane (g,lc) holds q=lc, k = ck*16 + g*4 + r
    f32x4 s[4];
#pragma unroll
    for (int ck = 0; ck < 4; ++ck) s[ck] = f32x4{0.f, 0.f, 0.f, 0.f};
    __builtin_amdgcn_s_setprio(1);
#pragma unroll
    for (int kk = 0; kk < 2; ++kk)
#pragma unroll
      for (int ck = 0; ck < 4; ++ck) {
        short8 bk = lds_frag(&Ks[cur][0], ck * 16 + lc, kk * 4 + g);
        s[ck] = mfma16(bk, aq[kk], s[ck]);
      }
    __builtin_amdgcn_s_setprio(0);

    // causal mask on the diagonal tile
    if (t == nt - 1) {
#pragma unroll
      for (int ck = 0; ck < 4; ++ck) {
        int kg = t * 64 + ck * 16 + g * 4;
        int qg = qs + lc;
#pragma unroll
        for (int r = 0; r < 4; ++r)
          if (kg + r > qg) s[ck][r] = -1e30f;
      }
    }

    // tile max per q-column (in-register 16 -> 1, then verified shfl reduce)
    float t0 = s[0][0];
#pragma unroll
    for (int ck = 0; ck < 4; ++ck)
#pragma unroll
      for (int r = 0; r < 4; ++r) t0 = fmaxf(t0, s[ck][r]);
    t0 = fmaxf(t0, __shfl_xor(t0, 16));
    t0 = fmaxf(t0, __shfl_xor(t0, 32));
    const float tmax = t0;

    // defer-max: rescale only when some column's max grew past THR=8 (log2)
    if (!__all(tmax <= m + 8.f)) {
      float mn = fmaxf(m, tmax);
      float al = exp2f(m - mn);
      m = mn;
      ls *= al;
#pragma unroll
      for (int r = 0; r < 4; ++r) {
        float alr = __shfl(al, g * 4 + r);  // col->row layout
#pragma unroll
        for (int dt = 0; dt < 4; ++dt) o[dt][r] *= alr;
      }
    }

    // P = exp2(S - m); row-sum; pack to PV A-fragments fully in-register.
    // pfrag[kk] lane (g,lc) = P[q=lc][32kk + 8g + 0..7]
    short8 pfrag[2];
    {
      float ps = 0.f;
      uint32_t d0[4], d1[4];
#pragma unroll
      for (int ck = 0; ck < 4; ++ck) {
        float e0 = exp2f(s[ck][0] - m);
        float e1 = exp2f(s[ck][1] - m);
        float e2 = exp2f(s[ck][2] - m);
        float e3 = exp2f(s[ck][3] - m);
        ps += (e0 + e1) + (e2 + e3);
        d0[ck] = cvtpk(e0, e1);
        d1[ck] = cvtpk(e2, e3);
      }
      ps += __shfl_xor(ps, 16);
      ps += __shfl_xor(ps, 32);
      ls += ps;
#pragma unroll
      for (int kk = 0; kk < 2; ++kk) {
        uint32_t A0 = d0[2 * kk], B0 = d0[2 * kk + 1];
        swap32(A0, B0); swap16(A0, B0);   // A0 = dw0, B0 = dw2
        uint32_t A1 = d1[2 * kk], B1 = d1[2 * kk + 1];
        swap32(A1, B1); swap16(A1, B1);   // A1 = dw1, B1 = dw3
        u32x4 u = {A0, A1, B0, B1};
        pfrag[kk] = __builtin_bit_cast(short8, u);
      }
    }

    // O += P V
    __builtin_amdgcn_s_setprio(1);
#pragma unroll
    for (int kk = 0; kk < 2; ++kk)
#pragma unroll
      for (int dt = 0; dt < 4; ++dt) {
        short8 bv = lds_frag(&Vs[cur][0], dt * 16 + lc, kk * 4 + g);
        o[dt] = mfma16(pfrag[kk], bv, o[dt]);
      }
    __builtin_amdgcn_s_setprio(0);

    __syncthreads();
  }

  // normalize + write (ls converted col->row once)
#pragma unroll
  for (int r = 0; r < 4; ++r) {
    float lsr = __shfl(ls, g * 4 + r);
    float inv = 1.0f / lsr;
#pragma unroll
    for (int dt = 0; dt < 4; ++dt) {
      float v = o[dt][r] * inv;
      AOb[(size_t)(qs + g * 4 + r) * 2048 + h * 64 + dt * 16 + lc] = f2b(v);
    }
  }
}

// ---------- output projection GEMM (bf16 in, fp32 out) ----------
__global__ __launch_bounds__(256) void out_gemm(
    const u16* __restrict__ A, const u16* __restrict__ W, float* __restrict__ C) {
  __shared__ __align__(16) u16 As[128 * 64];
  __shared__ __align__(16) u16 Bs[128 * 64];
  const int tid = threadIdx.x;
  const int l = tid & 63, w = tid >> 6;
  const int wm = w >> 1, wn = w & 1;
  const int bn = blockIdx.x, bm = blockIdx.y;

  f32x4 acc[4][4];
#pragma unroll
  for (int i = 0; i < 4; ++i)
#pragma unroll
    for (int j = 0; j < 4; ++j) acc[i][j] = f32x4{0.f, 0.f, 0.f, 0.f};

  const u16* Abase = A + (size_t)bm * 128 * 2048;
  const u16* Bbase = W + (size_t)bn * 128 * 2048;

  for (int kt = 0; kt < 32; ++kt) {
#pragma unroll
    for (int i = 0; i < 4; ++i) {
      int p = i * 256 + tid;
      int r = p >> 3;
      int c = (p & 7) ^ (r & 7);
      gload_lds16(Abase + (size_t)r * 2048 + kt * 64 + c * 8, As + p * 8);
      gload_lds16(Bbase + (size_t)r * 2048 + kt * 64 + c * 8, Bs + p * 8);
    }
    __syncthreads();
#pragma unroll
    for (int kk = 0; kk < 2; ++kk) {
      short8 af[4], bfr[4];
#pragma unroll
      for (int mi = 0; mi < 4; ++mi)
        af[mi] = lds_frag(As, wm * 64 + mi * 16 + (l & 15), kk * 4 + (l >> 4));
#pragma unroll
      for (int ni = 0; ni < 4; ++ni)
        bfr[ni] = lds_frag(Bs, wn * 64 + ni * 16 + (l & 15), kk * 4 + (l >> 4));
#pragma unroll
      for (int mi = 0; mi < 4; ++mi)
#pragma unroll
        for (int ni = 0; ni < 4; ++ni)
          acc[mi][ni] = mfma16(af[mi], bfr[ni], acc[mi][ni]);
    }
    __syncthreads();
  }

#pragma unroll
  for (int mi = 0; mi < 4; ++mi) {
    int srow0 = bm * 128 + wm * 64 + mi * 16 + (l >> 4) * 4;
#pragma unroll
    for (int ni = 0; ni < 4; ++ni) {
      int n = bn * 128 + wn * 64 + ni * 16 + (l & 15);
#pragma unroll
      for (int r = 0; r < 4; ++r)
        C[(size_t)(srow0 + r) * 2048 + n] = acc[mi][ni][r];
    }
  }
}

// ---------- launch ----------
extern "C" void kernel_launch(void* const* d_in, const int* in_sizes, int n_in,
                              void* d_out, int out_size, void* d_ws, size_t ws_size,
                              hipStream_t stream) {
  (void)in_sizes; (void)n_in; (void)out_size; (void)ws_size;
  const float* x  = (const float*)d_in[0];
  const float* wq = (const float*)d_in[1];
  const float* wk = (const float*)d_in[2];
  const float* wv = (const float*)d_in[3];
  const float* wo = (const float*)d_in[4];
  float* out = (float*)d_out;
  char* ws = (char*)d_ws;

  u16* xbf  = (u16*)(ws + 0);
  u16* wqbf = (u16*)(ws + 8388608);
  u16* wkbf = (u16*)(ws + 16777216);
  u16* wvbf = (u16*)(ws + 18874368);
  u16* wobf = (u16*)(ws + 20971520);
  u16* Qb   = (u16*)(ws + 29360128);
  u16* Kb   = (u16*)(ws + 37748736);
  u16* VTb  = (u16*)(ws + 39845888);
  u16* AOb  = (u16*)(ws + 41943040);

  cvt_kernel<<<2048, 256, 0, stream>>>(
      (const float4*)x, (const float4*)wq, (const float4*)wk,
      (const float4*)wv, (const float4*)wo,
      (ushort4*)xbf, (ushort4*)wqbf, (ushort4*)wkbf, (ushort4*)wvbf, (ushort4*)wobf);

  qkv_gemm<<<dim3(24, 16), 256, 0, stream>>>(xbf, wqbf, wkbf, wvbf, Qb, Kb, VTb);

  rope_kernel<<<(2048 * 1024 + 2048 * 256 + 255) / 256, 256, 0, stream>>>(Qb, Kb);

  attn_kernel<<<dim3(128, 8), 256, 0, stream>>>(Qb, Kb, VTb, AOb);

  out_gemm<<<dim3(16, 16), 256, 0, stream>>>(AOb, wobf, out);
}

// Round 7
// 144.017 us; speedup vs baseline: 1.5148x; 1.0983x over previous
//
#include <hip/hip_runtime.h>
#include <hip/hip_bf16.h>
#include <stdint.h>

#define DEVI __device__ __forceinline__

typedef unsigned short u16;
typedef __attribute__((ext_vector_type(8))) short short8;
typedef __attribute__((ext_vector_type(8))) __bf16 bf16x8;
typedef __attribute__((ext_vector_type(4))) float f32x4;
typedef __attribute__((ext_vector_type(4))) uint32_t u32x4;

// ---------- small helpers ----------
DEVI u16 f2b(float f) {
  __hip_bfloat16 h = __float2bfloat16(f);
  return __builtin_bit_cast(u16, h);
}
DEVI float b2f(u16 u) {
  union { float f; uint32_t i; } v;
  v.i = ((uint32_t)u) << 16;
  return v.f;
}

DEVI f32x4 mfma16(short8 a, short8 b, f32x4 c) {
  return __builtin_amdgcn_mfma_f32_16x16x32_bf16(
      __builtin_bit_cast(bf16x8, a), __builtin_bit_cast(bf16x8, b), c, 0, 0, 0);
}

// async global->LDS, 16B per lane; LDS dest = wave-uniform base + lane*16
DEVI void gload_lds16(const u16* g, u16* l) {
  __builtin_amdgcn_global_load_lds(
      (const __attribute__((address_space(1))) uint32_t*)g,
      (__attribute__((address_space(3))) uint32_t*)l, 16, 0, 0);
}

// Swizzled ds_read_b128 of an MFMA fragment from a [rows][64] bf16 tile
DEVI short8 lds_frag(const u16* base, int row, int col16) {
  int byte = (row << 7) ^ (col16 << 4) ^ ((row & 7) << 4);
  return *(const short8*)((const char*)base + byte);
}

// v_cvt_pk_bf16_f32: dst.lo = bf16(lo), dst.hi = bf16(hi)
DEVI uint32_t cvtpk(float lo, float hi) {
  uint32_t r;
  asm("v_cvt_pk_bf16_f32 %0, %1, %2" : "=v"(r) : "v"(lo), "v"(hi));
  return r;
}
// NOTE: operands must hold DISTINCT values (same-value operands get
// register-coalesced -> self-swap -> silent corruption; round-4 bug).
DEVI void swap32(uint32_t& a, uint32_t& b) {
  asm("v_permlane32_swap_b32 %0, %1" : "+v"(a), "+v"(b));
}
DEVI void swap16(uint32_t& a, uint32_t& b) {
  asm("v_permlane16_swap_b32 %0, %1" : "+v"(a), "+v"(b));
}

// ---------- fp32 -> bf16 conversion of inputs ----------
DEVI ushort4 cvt4(float4 v) {
  ushort4 o;
  o.x = f2b(v.x); o.y = f2b(v.y); o.z = f2b(v.z); o.w = f2b(v.w);
  return o;
}

__global__ void cvt_kernel(const float4* __restrict__ x, const float4* __restrict__ wq,
                           const float4* __restrict__ wk, const float4* __restrict__ wv,
                           const float4* __restrict__ wo,
                           ushort4* __restrict__ xb, ushort4* __restrict__ wqb,
                           ushort4* __restrict__ wkb, ushort4* __restrict__ wvb,
                           ushort4* __restrict__ wob) {
  int t = blockIdx.x * blockDim.x + threadIdx.x;
  int stride = gridDim.x * blockDim.x;
  for (int i = t; i < 1048576; i += stride) xb[i]  = cvt4(x[i]);
  for (int i = t; i < 1048576; i += stride) wqb[i] = cvt4(wq[i]);
  for (int i = t; i < 262144;  i += stride) wkb[i] = cvt4(wk[i]);
  for (int i = t; i < 262144;  i += stride) wvb[i] = cvt4(wv[i]);
  for (int i = t; i < 1048576; i += stride) wob[i] = cvt4(wo[i]);
}

// ---------- QKV projection GEMM (unchanged this round) ----------
__global__ __launch_bounds__(256) void qkv_gemm(
    const u16* __restrict__ X, const u16* __restrict__ WQ,
    const u16* __restrict__ WK, const u16* __restrict__ WV,
    u16* __restrict__ Qo, u16* __restrict__ Ko, u16* __restrict__ VTo) {
  __shared__ __align__(16) u16 As[128 * 64];
  __shared__ __align__(16) u16 Bs[128 * 64];
  const int tid = threadIdx.x;
  const int l = tid & 63, w = tid >> 6;
  const int wm = w >> 1, wn = w & 1;
  const int bn = blockIdx.x, bm = blockIdx.y;

  const u16* Wsrc;
  int nbase;
  if (bn < 16)      { Wsrc = WQ; nbase = bn * 128; }
  else if (bn < 20) { Wsrc = WK; nbase = bn * 128 - 2048; }
  else              { Wsrc = WV; nbase = bn * 128 - 2560; }

  f32x4 acc[4][4];
#pragma unroll
  for (int i = 0; i < 4; ++i)
#pragma unroll
    for (int j = 0; j < 4; ++j) acc[i][j] = f32x4{0.f, 0.f, 0.f, 0.f};

  const u16* Abase = X + (size_t)bm * 128 * 2048;

  for (int kt = 0; kt < 32; ++kt) {
#pragma unroll
    for (int i = 0; i < 4; ++i) {
      int p = i * 256 + tid;
      int r = p >> 3;
      int c = (p & 7) ^ (r & 7);
      gload_lds16(Abase + (size_t)r * 2048 + kt * 64 + c * 8, As + p * 8);
      gload_lds16(Wsrc + (size_t)(nbase + r) * 2048 + kt * 64 + c * 8, Bs + p * 8);
    }
    __syncthreads();
#pragma unroll
    for (int kk = 0; kk < 2; ++kk) {
      short8 af[4], bfr[4];
#pragma unroll
      for (int mi = 0; mi < 4; ++mi)
        af[mi] = lds_frag(As, wm * 64 + mi * 16 + (l & 15), kk * 4 + (l >> 4));
#pragma unroll
      for (int ni = 0; ni < 4; ++ni)
        bfr[ni] = lds_frag(Bs, wn * 64 + ni * 16 + (l & 15), kk * 4 + (l >> 4));
#pragma unroll
      for (int mi = 0; mi < 4; ++mi)
#pragma unroll
        for (int ni = 0; ni < 4; ++ni)
          acc[mi][ni] = mfma16(af[mi], bfr[ni], acc[mi][ni]);
    }
    __syncthreads();
  }

#pragma unroll
  for (int mi = 0; mi < 4; ++mi) {
    int srow0 = bm * 128 + wm * 64 + mi * 16 + (l >> 4) * 4;
#pragma unroll
    for (int ni = 0; ni < 4; ++ni) {
      int n = nbase + wn * 64 + ni * 16 + (l & 15);
      f32x4 v = acc[mi][ni];
      if (bn < 16) {
#pragma unroll
        for (int r = 0; r < 4; ++r)
          Qo[(size_t)(srow0 + r) * 2048 + n] = f2b(v[r]);
      } else if (bn < 20) {
#pragma unroll
        for (int r = 0; r < 4; ++r)
          Ko[(size_t)(srow0 + r) * 512 + n] = f2b(v[r]);
      } else {
        ushort4 pk;
        pk.x = f2b(v[0]); pk.y = f2b(v[1]); pk.z = f2b(v[2]); pk.w = f2b(v[3]);
        *(ushort4*)(VTo + (size_t)n * 2048 + srow0) = pk;
      }
    }
  }
}

// ---------- RoPE, vectorized short8 (4 pairs / thread; G13) ----------
__global__ void rope_kernel(u16* __restrict__ Qb, u16* __restrict__ Kb) {
  int idx = blockIdx.x * blockDim.x + threadIdx.x;
  const int NQC = 2048 * 256;           // Q: 2048 rows x 256 chunks of 8
  const int NTC = NQC + 2048 * 64;      // K: 2048 rows x 64 chunks
  if (idx >= NTC) return;
  u16* base;
  int s, hc;
  float scale;
  if (idx < NQC) {
    s = idx >> 8;
    int c = idx & 255;
    base = Qb + (size_t)s * 2048 + c * 8;
    hc = c & 7;
    scale = 0.18033688011112042f;  // 0.125 * log2(e) (exp2 softmax)
  } else {
    int j = idx - NQC;
    s = j >> 6;
    int c = j & 63;
    base = Kb + (size_t)s * 512 + c * 8;
    hc = c & 7;
    scale = 1.0f;
  }
  short8 v = *(const short8*)base;
  short8 ov;
  float fs = (float)s;
#pragma unroll
  for (int t = 0; t < 4; ++t) {
    float theta = exp2f(-(float)(hc * 4 + t) * 0.41524101186092034f);
    float sn, cs;
    sincosf(fs * theta, &sn, &cs);
    float x0 = b2f((u16)v[2 * t]), x1 = b2f((u16)v[2 * t + 1]);
    ov[2 * t]     = (short)f2b((x0 * cs - x1 * sn) * scale);
    ov[2 * t + 1] = (short)f2b((x1 * cs + x0 * sn) * scale);
  }
  *(short8*)base = ov;
}

// ---------- causal flash attention ----------
// grid (64, 8 kv-heads), 4 waves; wave w = q-head kvh*4+w, 16 q-rows.
// Each block processes TWO q-blocks sequentially (x and 127-x): every block
// runs 33-34 tiles -> uniform block lifetime, no occupancy-decay tail.
// 3-buffer K/V pipeline with counted s_waitcnt vmcnt(4) (T3/T4): one raw
// s_barrier per tile, stage(t+2) issued after it; no vmcnt(0) drain mid-loop.
// Row-sum ls computed by a ones-MFMA (lands row-layout, kills shfl chain).
DEVI void stage_kv(const u16* __restrict__ Kb, const u16* __restrict__ VTb,
                   u16* Ksb, u16* Vsb, int kvh, int t, int tid) {
#pragma unroll
  for (int i = 0; i < 2; ++i) {
    int p = i * 256 + tid;
    int r = p >> 3;
    int c = (p & 7) ^ (r & 7);
    gload_lds16(Kb + (size_t)(t * 64 + r) * 512 + kvh * 64 + c * 8, Ksb + p * 8);
    gload_lds16(VTb + (size_t)(kvh * 64 + r) * 2048 + t * 64 + c * 8, Vsb + p * 8);
  }
}

__global__ __launch_bounds__(256) void attn_kernel(
    const u16* __restrict__ Qb, const u16* __restrict__ Kb,
    const u16* __restrict__ VTb, u16* __restrict__ AOb) {
  __shared__ __align__(16) u16 Ks[3][64 * 64];
  __shared__ __align__(16) u16 Vs[3][64 * 64];
  const int tid = threadIdx.x;
  const int l = tid & 63, w = tid >> 6;
  const int kvh = blockIdx.y;
  const int x = blockIdx.x;
  const int h = kvh * 4 + w;
  const int g = l >> 4;          // lane group 0..3
  const int lc = l & 15;         // lane column 0..15
  const short8 ONES = {16256, 16256, 16256, 16256, 16256, 16256, 16256, 16256};  // bf16 1.0

  for (int half = 0; half < 2; ++half) {
    const int qb = half ? (127 - x) : x;
    const int qs = qb * 16;
    const int nt = (qb >> 2) + 1;

    // Q fragments (B-operand of swapped QK): lane holds Q[q=qs+lc][d-range]
    const u16* qp = Qb + (size_t)(qs + lc) * 2048 + h * 64 + g * 8;
    short8 aq0 = *(const short8*)qp;
    short8 aq1 = *(const short8*)(qp + 32);

    float m = -1e30f;
    f32x4 o[4];
    f32x4 ols = f32x4{0.f, 0.f, 0.f, 0.f};
#pragma unroll
    for (int dt = 0; dt < 4; ++dt) o[dt] = f32x4{0.f, 0.f, 0.f, 0.f};

    __syncthreads();  // previous half's LDS reads fully done before restaging
    stage_kv(Kb, VTb, Ks[0], Vs[0], kvh, 0, tid);
    if (nt > 1) stage_kv(Kb, VTb, Ks[1], Vs[1], kvh, 1, tid);

    for (int t = 0; t < nt; ++t) {
      const u16* ks = Ks[t % 3];
      const u16* vs = Vs[t % 3];
      // wait for stage(t) only; keep stage(t+1)'s 4 loads in flight
      if (t + 1 < nt) { asm volatile("s_waitcnt vmcnt(4)" ::: "memory"); }
      else            { asm volatile("s_waitcnt vmcnt(0)" ::: "memory"); }
      __builtin_amdgcn_s_barrier();
      __builtin_amdgcn_sched_barrier(0);
      if (t + 2 < nt) stage_kv(Kb, VTb, Ks[(t + 2) % 3], Vs[(t + 2) % 3], kvh, t + 2, tid);

      // S^T[k][q] = K Q^T : lane (g,lc) holds q=lc, k = ck*16 + g*4 + r
      f32x4 s[4];
#pragma unroll
      for (int ck = 0; ck < 4; ++ck) s[ck] = f32x4{0.f, 0.f, 0.f, 0.f};
      __builtin_amdgcn_s_setprio(1);
#pragma unroll
      for (int kk = 0; kk < 2; ++kk)
#pragma unroll
        for (int ck = 0; ck < 4; ++ck) {
          short8 bk = lds_frag(ks, ck * 16 + lc, kk * 4 + g);
          s[ck] = mfma16(bk, kk ? aq1 : aq0, s[ck]);
        }
      __builtin_amdgcn_s_setprio(0);

      // causal mask on the diagonal tile
      if (t == nt - 1) {
#pragma unroll
        for (int ck = 0; ck < 4; ++ck) {
          int kg = t * 64 + ck * 16 + g * 4;
          int qg = qs + lc;
#pragma unroll
          for (int r = 0; r < 4; ++r)
            if (kg + r > qg) s[ck][r] = -1e30f;
        }
      }

      // tile max per q-column (in-register 16 -> 1, then shfl reduce)
      float t0 = s[0][0];
#pragma unroll
      for (int ck = 0; ck < 4; ++ck)
#pragma unroll
        for (int r = 0; r < 4; ++r) t0 = fmaxf(t0, s[ck][r]);
      t0 = fmaxf(t0, __shfl_xor(t0, 16));
      t0 = fmaxf(t0, __shfl_xor(t0, 32));
      const float tmax = t0;

      // defer-max: rescale only when some column's max grew past THR=8 (log2)
      if (!__all(tmax <= m + 8.f)) {
        float mn = fmaxf(m, tmax);
        float al = exp2f(m - mn);
        m = mn;
#pragma unroll
        for (int r = 0; r < 4; ++r) {
          float alr = __shfl(al, g * 4 + r);  // col->row layout
          ols[r] *= alr;
#pragma unroll
          for (int dt = 0; dt < 4; ++dt) o[dt][r] *= alr;
        }
      }

      // P = exp2(S - m); pack to PV A-fragments in-register (cvt_pk+permlane)
      short8 pfrag[2];
      {
        uint32_t d0[4], d1[4];
#pragma unroll
        for (int ck = 0; ck < 4; ++ck) {
          float e0 = exp2f(s[ck][0] - m);
          float e1 = exp2f(s[ck][1] - m);
          float e2 = exp2f(s[ck][2] - m);
          float e3 = exp2f(s[ck][3] - m);
          d0[ck] = cvtpk(e0, e1);
          d1[ck] = cvtpk(e2, e3);
        }
#pragma unroll
        for (int kk = 0; kk < 2; ++kk) {
          uint32_t A0 = d0[2 * kk], B0 = d0[2 * kk + 1];
          swap32(A0, B0); swap16(A0, B0);
          uint32_t A1 = d1[2 * kk], B1 = d1[2 * kk + 1];
          swap32(A1, B1); swap16(A1, B1);
          u32x4 u = {A0, A1, B0, B1};
          pfrag[kk] = __builtin_bit_cast(short8, u);
        }
      }

      // O += P V ; ls += P * ones (row-sum in row layout, replaces shfl chain)
      __builtin_amdgcn_s_setprio(1);
#pragma unroll
      for (int kk = 0; kk < 2; ++kk) {
#pragma unroll
        for (int dt = 0; dt < 4; ++dt) {
          short8 bv = lds_frag(vs, dt * 16 + lc, kk * 4 + g);
          o[dt] = mfma16(pfrag[kk], bv, o[dt]);
        }
        ols = mfma16(pfrag[kk], ONES, ols);
      }
      __builtin_amdgcn_s_setprio(0);
    }

    // normalize + write (ols already in row layout q = qs + g*4 + r)
#pragma unroll
    for (int r = 0; r < 4; ++r) {
      float inv = 1.0f / ols[r];
#pragma unroll
      for (int dt = 0; dt < 4; ++dt) {
        float v = o[dt][r] * inv;
        AOb[(size_t)(qs + g * 4 + r) * 2048 + h * 64 + dt * 16 + lc] = f2b(v);
      }
    }
  }
}

// ---------- output projection GEMM, 128x64 tile (2 blocks/CU; was 1) ----------
__global__ __launch_bounds__(256) void out_gemm(
    const u16* __restrict__ A, const u16* __restrict__ W, float* __restrict__ C) {
  __shared__ __align__(16) u16 As[128 * 64];
  __shared__ __align__(16) u16 Bs[64 * 64];
  const int tid = threadIdx.x;
  const int l = tid & 63, w = tid >> 6;
  const int wm = w >> 1, wn = w & 1;
  const int bn = blockIdx.x, bm = blockIdx.y;
  const int g = l >> 4, lc = l & 15;

  f32x4 acc[4][2];
#pragma unroll
  for (int i = 0; i < 4; ++i)
#pragma unroll
    for (int j = 0; j < 2; ++j) acc[i][j] = f32x4{0.f, 0.f, 0.f, 0.f};

  const u16* Abase = A + (size_t)bm * 128 * 2048;
  const u16* Bbase = W + (size_t)bn * 64 * 2048;

  for (int kt = 0; kt < 32; ++kt) {
#pragma unroll
    for (int i = 0; i < 4; ++i) {
      int p = i * 256 + tid;
      int r = p >> 3;
      int c = (p & 7) ^ (r & 7);
      gload_lds16(Abase + (size_t)r * 2048 + kt * 64 + c * 8, As + p * 8);
    }
#pragma unroll
    for (int i = 0; i < 2; ++i) {
      int p = i * 256 + tid;
      int r = p >> 3;
      int c = (p & 7) ^ (r & 7);
      gload_lds16(Bbase + (size_t)r * 2048 + kt * 64 + c * 8, Bs + p * 8);
    }
    __syncthreads();
#pragma unroll
    for (int kk = 0; kk < 2; ++kk) {
      short8 af[4], bfr[2];
#pragma unroll
      for (int mi = 0; mi < 4; ++mi)
        af[mi] = lds_frag(As, wm * 64 + mi * 16 + lc, kk * 4 + g);
#pragma unroll
      for (int ni = 0; ni < 2; ++ni)
        bfr[ni] = lds_frag(Bs, wn * 32 + ni * 16 + lc, kk * 4 + g);
#pragma unroll
      for (int mi = 0; mi < 4; ++mi)
#pragma unroll
        for (int ni = 0; ni < 2; ++ni)
          acc[mi][ni] = mfma16(af[mi], bfr[ni], acc[mi][ni]);
    }
    __syncthreads();
  }

#pragma unroll
  for (int mi = 0; mi < 4; ++mi) {
    int srow0 = bm * 128 + wm * 64 + mi * 16 + g * 4;
#pragma unroll
    for (int ni = 0; ni < 2; ++ni) {
      int n = bn * 64 + wn * 32 + ni * 16 + lc;
#pragma unroll
      for (int r = 0; r < 4; ++r)
        C[(size_t)(srow0 + r) * 2048 + n] = acc[mi][ni][r];
    }
  }
}

// ---------- launch ----------
extern "C" void kernel_launch(void* const* d_in, const int* in_sizes, int n_in,
                              void* d_out, int out_size, void* d_ws, size_t ws_size,
                              hipStream_t stream) {
  (void)in_sizes; (void)n_in; (void)out_size; (void)ws_size;
  const float* x  = (const float*)d_in[0];
  const float* wq = (const float*)d_in[1];
  const float* wk = (const float*)d_in[2];
  const float* wv = (const float*)d_in[3];
  const float* wo = (const float*)d_in[4];
  float* out = (float*)d_out;
  char* ws = (char*)d_ws;

  u16* xbf  = (u16*)(ws + 0);
  u16* wqbf = (u16*)(ws + 8388608);
  u16* wkbf = (u16*)(ws + 16777216);
  u16* wvbf = (u16*)(ws + 18874368);
  u16* wobf = (u16*)(ws + 20971520);
  u16* Qb   = (u16*)(ws + 29360128);
  u16* Kb   = (u16*)(ws + 37748736);
  u16* VTb  = (u16*)(ws + 39845888);
  u16* AOb  = (u16*)(ws + 41943040);

  cvt_kernel<<<2048, 256, 0, stream>>>(
      (const float4*)x, (const float4*)wq, (const float4*)wk,
      (const float4*)wv, (const float4*)wo,
      (ushort4*)xbf, (ushort4*)wqbf, (ushort4*)wkbf, (ushort4*)wvbf, (ushort4*)wobf);

  qkv_gemm<<<dim3(24, 16), 256, 0, stream>>>(xbf, wqbf, wkbf, wvbf, Qb, Kb, VTb);

  rope_kernel<<<(2048 * 256 + 2048 * 64 + 255) / 256, 256, 0, stream>>>(Qb, Kb);

  attn_kernel<<<dim3(64, 8), 256, 0, stream>>>(Qb, Kb, VTb, AOb);

  out_gemm<<<dim3(32, 16), 256, 0, stream>>>(AOb, wobf, out);
}

// Round 8
// 130.348 us; speedup vs baseline: 1.6736x; 1.1049x over previous
//
#include <hip/hip_runtime.h>
#include <hip/hip_bf16.h>
#include <stdint.h>

#define DEVI __device__ __forceinline__

typedef unsigned short u16;
typedef __attribute__((ext_vector_type(8))) short short8;
typedef __attribute__((ext_vector_type(8))) __bf16 bf16x8;
typedef __attribute__((ext_vector_type(4))) float f32x4;
typedef __attribute__((ext_vector_type(4))) uint32_t u32x4;

// ---------- small helpers ----------
DEVI u16 f2b(float f) {
  __hip_bfloat16 h = __float2bfloat16(f);
  return __builtin_bit_cast(u16, h);
}
DEVI float b2f(u16 u) {
  union { float f; uint32_t i; } v;
  v.i = ((uint32_t)u) << 16;
  return v.f;
}

DEVI f32x4 mfma16(short8 a, short8 b, f32x4 c) {
  return __builtin_amdgcn_mfma_f32_16x16x32_bf16(
      __builtin_bit_cast(bf16x8, a), __builtin_bit_cast(bf16x8, b), c, 0, 0, 0);
}

// async global->LDS, 16B per lane; LDS dest = wave-uniform base + lane*16
DEVI void gload_lds16(const u16* g, u16* l) {
  __builtin_amdgcn_global_load_lds(
      (const __attribute__((address_space(1))) uint32_t*)g,
      (__attribute__((address_space(3))) uint32_t*)l, 16, 0, 0);
}

// Swizzled ds_read_b128 of an MFMA fragment from a [rows][64] bf16 tile
DEVI short8 lds_frag(const u16* base, int row, int col16) {
  int byte = (row << 7) ^ (col16 << 4) ^ ((row & 7) << 4);
  return *(const short8*)((const char*)base + byte);
}

// v_cvt_pk_bf16_f32: dst.lo = bf16(lo), dst.hi = bf16(hi)
DEVI uint32_t cvtpk(float lo, float hi) {
  uint32_t r;
  asm("v_cvt_pk_bf16_f32 %0, %1, %2" : "=v"(r) : "v"(lo), "v"(hi));
  return r;
}
// NOTE: operands must hold DISTINCT registers (same-value operands get
// register-coalesced -> self-swap -> silent corruption; round-4 bug).
DEVI void swap32(uint32_t& a, uint32_t& b) {
  asm("v_permlane32_swap_b32 %0, %1" : "+v"(a), "+v"(b));
}
DEVI void swap16(uint32_t& a, uint32_t& b) {
  asm("v_permlane16_swap_b32 %0, %1" : "+v"(a), "+v"(b));
}
// opaque copy -> guarantees a distinct register for the swap partner
DEVI uint32_t opaque_copy(uint32_t a) {
  uint32_t b;
  asm("v_mov_b32 %0, %1" : "=v"(b) : "v"(a));
  return b;
}
// max over the 4 lane-groups (lanes sharing l&15), VALU-only (no ds_permute):
// permlane16_swap pair-exchanges 16-lane rows {0<->1, 2<->3} when fed two
// copies; permlane32_swap exchanges row-pairs {01 <-> 23}. fmax after each
// gives the full 4-group reduction in ~4 VALU ops.
DEVI float redmax64(float t) {
  uint32_t a = __builtin_bit_cast(uint32_t, t);
  uint32_t b = opaque_copy(a);
  swap16(a, b);
  float t2 = fmaxf(__builtin_bit_cast(float, a), __builtin_bit_cast(float, b));
  uint32_t c = __builtin_bit_cast(uint32_t, t2);
  uint32_t d = opaque_copy(c);
  swap32(c, d);
  return fmaxf(__builtin_bit_cast(float, c), __builtin_bit_cast(float, d));
}

// ---------- fp32 -> bf16 conversion of inputs ----------
DEVI ushort4 cvt4(float4 v) {
  ushort4 o;
  o.x = f2b(v.x); o.y = f2b(v.y); o.z = f2b(v.z); o.w = f2b(v.w);
  return o;
}

__global__ void cvt_kernel(const float4* __restrict__ x, const float4* __restrict__ wq,
                           const float4* __restrict__ wk, const float4* __restrict__ wv,
                           const float4* __restrict__ wo,
                           ushort4* __restrict__ xb, ushort4* __restrict__ wqb,
                           ushort4* __restrict__ wkb, ushort4* __restrict__ wvb,
                           ushort4* __restrict__ wob) {
  int t = blockIdx.x * blockDim.x + threadIdx.x;
  int stride = gridDim.x * blockDim.x;
  for (int i = t; i < 1048576; i += stride) xb[i]  = cvt4(x[i]);
  for (int i = t; i < 1048576; i += stride) wqb[i] = cvt4(wq[i]);
  for (int i = t; i < 262144;  i += stride) wkb[i] = cvt4(wk[i]);
  for (int i = t; i < 262144;  i += stride) wvb[i] = cvt4(wv[i]);
  for (int i = t; i < 1048576; i += stride) wob[i] = cvt4(wo[i]);
}

// ---------- QKV projection GEMM, 128x64 tile (3 blocks/CU; was 1.5) ----------
// C[s][n] = sum_e X[s][e]*W[n][e]; N-space: Q bn<32, K bn 32..39, V bn 40..47.
__global__ __launch_bounds__(256) void qkv_gemm(
    const u16* __restrict__ X, const u16* __restrict__ WQ,
    const u16* __restrict__ WK, const u16* __restrict__ WV,
    u16* __restrict__ Qo, u16* __restrict__ Ko, u16* __restrict__ VTo) {
  __shared__ __align__(16) u16 As[128 * 64];
  __shared__ __align__(16) u16 Bs[64 * 64];
  const int tid = threadIdx.x;
  const int l = tid & 63, w = tid >> 6;
  const int wm = w >> 1, wn = w & 1;
  const int bn = blockIdx.x, bm = blockIdx.y;
  const int g = l >> 4, lc = l & 15;

  const u16* Wsrc;
  int nbase;
  if (bn < 32)      { Wsrc = WQ; nbase = bn * 64; }
  else if (bn < 40) { Wsrc = WK; nbase = bn * 64 - 2048; }
  else              { Wsrc = WV; nbase = bn * 64 - 2560; }

  f32x4 acc[4][2];
#pragma unroll
  for (int i = 0; i < 4; ++i)
#pragma unroll
    for (int j = 0; j < 2; ++j) acc[i][j] = f32x4{0.f, 0.f, 0.f, 0.f};

  const u16* Abase = X + (size_t)bm * 128 * 2048;

  for (int kt = 0; kt < 32; ++kt) {
#pragma unroll
    for (int i = 0; i < 4; ++i) {
      int p = i * 256 + tid;
      int r = p >> 3;
      int c = (p & 7) ^ (r & 7);
      gload_lds16(Abase + (size_t)r * 2048 + kt * 64 + c * 8, As + p * 8);
    }
#pragma unroll
    for (int i = 0; i < 2; ++i) {
      int p = i * 256 + tid;
      int r = p >> 3;
      int c = (p & 7) ^ (r & 7);
      gload_lds16(Wsrc + (size_t)(nbase + r) * 2048 + kt * 64 + c * 8, Bs + p * 8);
    }
    __syncthreads();
#pragma unroll
    for (int kk = 0; kk < 2; ++kk) {
      short8 af[4], bfr[2];
#pragma unroll
      for (int mi = 0; mi < 4; ++mi)
        af[mi] = lds_frag(As, wm * 64 + mi * 16 + lc, kk * 4 + g);
#pragma unroll
      for (int ni = 0; ni < 2; ++ni)
        bfr[ni] = lds_frag(Bs, wn * 32 + ni * 16 + lc, kk * 4 + g);
#pragma unroll
      for (int mi = 0; mi < 4; ++mi)
#pragma unroll
        for (int ni = 0; ni < 2; ++ni)
          acc[mi][ni] = mfma16(af[mi], bfr[ni], acc[mi][ni]);
    }
    __syncthreads();
  }

#pragma unroll
  for (int mi = 0; mi < 4; ++mi) {
    int srow0 = bm * 128 + wm * 64 + mi * 16 + g * 4;
#pragma unroll
    for (int ni = 0; ni < 2; ++ni) {
      int n = nbase + wn * 32 + ni * 16 + lc;
      f32x4 v = acc[mi][ni];
      if (bn < 32) {
#pragma unroll
        for (int r = 0; r < 4; ++r)
          Qo[(size_t)(srow0 + r) * 2048 + n] = f2b(v[r]);
      } else if (bn < 40) {
#pragma unroll
        for (int r = 0; r < 4; ++r)
          Ko[(size_t)(srow0 + r) * 512 + n] = f2b(v[r]);
      } else {
        ushort4 pk;
        pk.x = f2b(v[0]); pk.y = f2b(v[1]); pk.z = f2b(v[2]); pk.w = f2b(v[3]);
        *(ushort4*)(VTo + (size_t)n * 2048 + srow0) = pk;
      }
    }
  }
}

// ---------- RoPE, vectorized short8 (4 pairs / thread; G13) ----------
__global__ void rope_kernel(u16* __restrict__ Qb, u16* __restrict__ Kb) {
  int idx = blockIdx.x * blockDim.x + threadIdx.x;
  const int NQC = 2048 * 256;           // Q: 2048 rows x 256 chunks of 8
  const int NTC = NQC + 2048 * 64;      // K: 2048 rows x 64 chunks
  if (idx >= NTC) return;
  u16* base;
  int s, hc;
  float scale;
  if (idx < NQC) {
    s = idx >> 8;
    int c = idx & 255;
    base = Qb + (size_t)s * 2048 + c * 8;
    hc = c & 7;
    scale = 0.18033688011112042f;  // 0.125 * log2(e) (exp2 softmax)
  } else {
    int j = idx - NQC;
    s = j >> 6;
    int c = j & 63;
    base = Kb + (size_t)s * 512 + c * 8;
    hc = c & 7;
    scale = 1.0f;
  }
  short8 v = *(const short8*)base;
  short8 ov;
  float fs = (float)s;
#pragma unroll
  for (int t = 0; t < 4; ++t) {
    float theta = exp2f(-(float)(hc * 4 + t) * 0.41524101186092034f);
    float sn, cs;
    sincosf(fs * theta, &sn, &cs);
    float x0 = b2f((u16)v[2 * t]), x1 = b2f((u16)v[2 * t + 1]);
    ov[2 * t]     = (short)f2b((x0 * cs - x1 * sn) * scale);
    ov[2 * t + 1] = (short)f2b((x1 * cs + x0 * sn) * scale);
  }
  *(short8*)base = ov;
}

// ---------- causal flash attention ----------
// grid (128, 8 kv-heads), 4 waves; wave w = q-head kvh*4+w, 16 q-rows.
// 2-buffer LDS (32KB) -> 4 blocks/CU: ALL 1024 blocks resident, no tail.
// Co-residency balance: CU gets ids {c, c+256, c+512, c+768} = same x with
// y in {y0,y0+2,..}; qb = (kvh<4 ? 127-x : x) -> per-CU tiles = 66 +- 1.
// Per tile: barrier1 (write-after-read guard) -> stage(t+1) -> counted
// vmcnt(4) -> barrier2 (stage(t) visible) -> compute. Never vmcnt(0) mid-loop.
// tmax reduce via permlane16/32_swap (VALU) instead of ds_permute shuffles.
DEVI void stage_kv(const u16* __restrict__ Kb, const u16* __restrict__ VTb,
                   u16* Ksb, u16* Vsb, int kvh, int t, int tid) {
#pragma unroll
  for (int i = 0; i < 2; ++i) {
    int p = i * 256 + tid;
    int r = p >> 3;
    int c = (p & 7) ^ (r & 7);
    gload_lds16(Kb + (size_t)(t * 64 + r) * 512 + kvh * 64 + c * 8, Ksb + p * 8);
    gload_lds16(VTb + (size_t)(kvh * 64 + r) * 2048 + t * 64 + c * 8, Vsb + p * 8);
  }
}

__global__ __launch_bounds__(256, 4) void attn_kernel(
    const u16* __restrict__ Qb, const u16* __restrict__ Kb,
    const u16* __restrict__ VTb, u16* __restrict__ AOb) {
  __shared__ __align__(16) u16 Ks[2][64 * 64];
  __shared__ __align__(16) u16 Vs[2][64 * 64];
  const int tid = threadIdx.x;
  const int l = tid & 63, w = tid >> 6;
  const int kvh = blockIdx.y;
  const int x = blockIdx.x;
  const int qb = (kvh < 4) ? (127 - x) : x;
  const int h = kvh * 4 + w;
  const int qs = qb * 16;
  const int nt = (qb >> 2) + 1;
  const int g = l >> 4;          // lane group 0..3
  const int lc = l & 15;         // lane column 0..15
  const short8 ONES = {16256, 16256, 16256, 16256, 16256, 16256, 16256, 16256};  // bf16 1.0

  // Q fragments (B-operand of swapped QK): lane holds Q[q=qs+lc][d-range]
  const u16* qp = Qb + (size_t)(qs + lc) * 2048 + h * 64 + g * 8;
  short8 aq0 = *(const short8*)qp;
  short8 aq1 = *(const short8*)(qp + 32);

  float m = -1e30f;
  f32x4 o[4];
  f32x4 ols = f32x4{0.f, 0.f, 0.f, 0.f};
#pragma unroll
  for (int dt = 0; dt < 4; ++dt) o[dt] = f32x4{0.f, 0.f, 0.f, 0.f};

  stage_kv(Kb, VTb, Ks[0], Vs[0], kvh, 0, tid);

  for (int t = 0; t < nt; ++t) {
    const u16* ks = Ks[t & 1];
    const u16* vs = Vs[t & 1];

    // barrier1: all waves finished compute(t-1) -> safe to overwrite buf[(t+1)&1]
    __builtin_amdgcn_s_barrier();
    __builtin_amdgcn_sched_barrier(0);
    if (t + 1 < nt) {
      stage_kv(Kb, VTb, Ks[(t + 1) & 1], Vs[(t + 1) & 1], kvh, t + 1, tid);
      asm volatile("s_waitcnt vmcnt(4)" ::: "memory");  // my stage(t) done
    } else {
      asm volatile("s_waitcnt vmcnt(0)" ::: "memory");
    }
    // barrier2: every wave's stage(t) portion landed in LDS
    __builtin_amdgcn_s_barrier();
    __builtin_amdgcn_sched_barrier(0);

    // S^T[k][q] = K Q^T : lane (g,lc) holds q=lc, k = ck*16 + g*4 + r
    f32x4 s[4];
#pragma unroll
    for (int ck = 0; ck < 4; ++ck) s[ck] = f32x4{0.f, 0.f, 0.f, 0.f};
    __builtin_amdgcn_s_setprio(1);
#pragma unroll
    for (int kk = 0; kk < 2; ++kk)
#pragma unroll
      for (int ck = 0; ck < 4; ++ck) {
        short8 bk = lds_frag(ks, ck * 16 + lc, kk * 4 + g);
        s[ck] = mfma16(bk, kk ? aq1 : aq0, s[ck]);
      }
    __builtin_amdgcn_s_setprio(0);

    // causal mask on the diagonal tile
    if (t == nt - 1) {
#pragma unroll
      for (int ck = 0; ck < 4; ++ck) {
        int kg = t * 64 + ck * 16 + g * 4;
        int qg = qs + lc;
#pragma unroll
        for (int r = 0; r < 4; ++r)
          if (kg + r > qg) s[ck][r] = -1e30f;
      }
    }

    // tile max per q-column: in-register (max3-friendly triples) + permlane
    float t0 = fmaxf(fmaxf(s[0][0], s[0][1]), fmaxf(s[0][2], s[0][3]));
    float t1 = fmaxf(fmaxf(s[1][0], s[1][1]), fmaxf(s[1][2], s[1][3]));
    float t2 = fmaxf(fmaxf(s[2][0], s[2][1]), fmaxf(s[2][2], s[2][3]));
    float t3 = fmaxf(fmaxf(s[3][0], s[3][1]), fmaxf(s[3][2], s[3][3]));
    const float tmax = redmax64(fmaxf(fmaxf(t0, t1), fmaxf(t2, t3)));

    // defer-max: rescale only when some column's max grew past THR=8 (log2)
    if (!__all(tmax <= m + 8.f)) {
      float mn = fmaxf(m, tmax);
      float al = exp2f(m - mn);
      m = mn;
#pragma unroll
      for (int r = 0; r < 4; ++r) {
        float alr = __shfl(al, g * 4 + r);  // col->row layout
        ols[r] *= alr;
#pragma unroll
        for (int dt = 0; dt < 4; ++dt) o[dt][r] *= alr;
      }
    }

    // P = exp2(S - m); pack to PV A-fragments in-register (cvt_pk+permlane)
    short8 pfrag[2];
    {
      uint32_t d0[4], d1[4];
#pragma unroll
      for (int ck = 0; ck < 4; ++ck) {
        float e0 = exp2f(s[ck][0] - m);
        float e1 = exp2f(s[ck][1] - m);
        float e2 = exp2f(s[ck][2] - m);
        float e3 = exp2f(s[ck][3] - m);
        d0[ck] = cvtpk(e0, e1);
        d1[ck] = cvtpk(e2, e3);
      }
#pragma unroll
      for (int kk = 0; kk < 2; ++kk) {
        uint32_t A0 = d0[2 * kk], B0 = d0[2 * kk + 1];
        swap32(A0, B0); swap16(A0, B0);
        uint32_t A1 = d1[2 * kk], B1 = d1[2 * kk + 1];
        swap32(A1, B1); swap16(A1, B1);
        u32x4 u = {A0, A1, B0, B1};
        pfrag[kk] = __builtin_bit_cast(short8, u);
      }
    }

    // O += P V ; ls += P * ones (row-sum in row layout)
    __builtin_amdgcn_s_setprio(1);
#pragma unroll
    for (int kk = 0; kk < 2; ++kk) {
#pragma unroll
      for (int dt = 0; dt < 4; ++dt) {
        short8 bv = lds_frag(vs, dt * 16 + lc, kk * 4 + g);
        o[dt] = mfma16(pfrag[kk], bv, o[dt]);
      }
      ols = mfma16(pfrag[kk], ONES, ols);
    }
    __builtin_amdgcn_s_setprio(0);
  }

  // normalize + write (ols already in row layout q = qs + g*4 + r)
#pragma unroll
  for (int r = 0; r < 4; ++r) {
    float inv = 1.0f / ols[r];
#pragma unroll
    for (int dt = 0; dt < 4; ++dt) {
      float v = o[dt][r] * inv;
      AOb[(size_t)(qs + g * 4 + r) * 2048 + h * 64 + dt * 16 + lc] = f2b(v);
    }
  }
}

// ---------- output projection GEMM, 128x64 tile (2 blocks/CU) ----------
__global__ __launch_bounds__(256) void out_gemm(
    const u16* __restrict__ A, const u16* __restrict__ W, float* __restrict__ C) {
  __shared__ __align__(16) u16 As[128 * 64];
  __shared__ __align__(16) u16 Bs[64 * 64];
  const int tid = threadIdx.x;
  const int l = tid & 63, w = tid >> 6;
  const int wm = w >> 1, wn = w & 1;
  const int bn = blockIdx.x, bm = blockIdx.y;
  const int g = l >> 4, lc = l & 15;

  f32x4 acc[4][2];
#pragma unroll
  for (int i = 0; i < 4; ++i)
#pragma unroll
    for (int j = 0; j < 2; ++j) acc[i][j] = f32x4{0.f, 0.f, 0.f, 0.f};

  const u16* Abase = A + (size_t)bm * 128 * 2048;
  const u16* Bbase = W + (size_t)bn * 64 * 2048;

  for (int kt = 0; kt < 32; ++kt) {
#pragma unroll
    for (int i = 0; i < 4; ++i) {
      int p = i * 256 + tid;
      int r = p >> 3;
      int c = (p & 7) ^ (r & 7);
      gload_lds16(Abase + (size_t)r * 2048 + kt * 64 + c * 8, As + p * 8);
    }
#pragma unroll
    for (int i = 0; i < 2; ++i) {
      int p = i * 256 + tid;
      int r = p >> 3;
      int c = (p & 7) ^ (r & 7);
      gload_lds16(Bbase + (size_t)r * 2048 + kt * 64 + c * 8, Bs + p * 8);
    }
    __syncthreads();
#pragma unroll
    for (int kk = 0; kk < 2; ++kk) {
      short8 af[4], bfr[2];
#pragma unroll
      for (int mi = 0; mi < 4; ++mi)
        af[mi] = lds_frag(As, wm * 64 + mi * 16 + lc, kk * 4 + g);
#pragma unroll
      for (int ni = 0; ni < 2; ++ni)
        bfr[ni] = lds_frag(Bs, wn * 32 + ni * 16 + lc, kk * 4 + g);
#pragma unroll
      for (int mi = 0; mi < 4; ++mi)
#pragma unroll
        for (int ni = 0; ni < 2; ++ni)
          acc[mi][ni] = mfma16(af[mi], bfr[ni], acc[mi][ni]);
    }
    __syncthreads();
  }

#pragma unroll
  for (int mi = 0; mi < 4; ++mi) {
    int srow0 = bm * 128 + wm * 64 + mi * 16 + g * 4;
#pragma unroll
    for (int ni = 0; ni < 2; ++ni) {
      int n = bn * 64 + wn * 32 + ni * 16 + lc;
#pragma unroll
      for (int r = 0; r < 4; ++r)
        C[(size_t)(srow0 + r) * 2048 + n] = acc[mi][ni][r];
    }
  }
}

// ---------- launch ----------
extern "C" void kernel_launch(void* const* d_in, const int* in_sizes, int n_in,
                              void* d_out, int out_size, void* d_ws, size_t ws_size,
                              hipStream_t stream) {
  (void)in_sizes; (void)n_in; (void)out_size; (void)ws_size;
  const float* x  = (const float*)d_in[0];
  const float* wq = (const float*)d_in[1];
  const float* wk = (const float*)d_in[2];
  const float* wv = (const float*)d_in[3];
  const float* wo = (const float*)d_in[4];
  float* out = (float*)d_out;
  char* ws = (char*)d_ws;

  u16* xbf  = (u16*)(ws + 0);
  u16* wqbf = (u16*)(ws + 8388608);
  u16* wkbf = (u16*)(ws + 16777216);
  u16* wvbf = (u16*)(ws + 18874368);
  u16* wobf = (u16*)(ws + 20971520);
  u16* Qb   = (u16*)(ws + 29360128);
  u16* Kb   = (u16*)(ws + 37748736);
  u16* VTb  = (u16*)(ws + 39845888);
  u16* AOb  = (u16*)(ws + 41943040);

  cvt_kernel<<<2048, 256, 0, stream>>>(
      (const float4*)x, (const float4*)wq, (const float4*)wk,
      (const float4*)wv, (const float4*)wo,
      (ushort4*)xbf, (ushort4*)wqbf, (ushort4*)wkbf, (ushort4*)wvbf, (ushort4*)wobf);

  qkv_gemm<<<dim3(48, 16), 256, 0, stream>>>(xbf, wqbf, wkbf, wvbf, Qb, Kb, VTb);

  rope_kernel<<<(2048 * 256 + 2048 * 64 + 255) / 256, 256, 0, stream>>>(Qb, Kb);

  attn_kernel<<<dim3(128, 8), 256, 0, stream>>>(Qb, Kb, VTb, AOb);

  out_gemm<<<dim3(32, 16), 256, 0, stream>>>(AOb, wobf, out);
}

// Round 9
// 124.951 us; speedup vs baseline: 1.7459x; 1.0432x over previous
//
#include <hip/hip_runtime.h>
#include <hip/hip_bf16.h>
#include <stdint.h>

#define DEVI __device__ __forceinline__

typedef unsigned short u16;
typedef __attribute__((ext_vector_type(8))) short short8;
typedef __attribute__((ext_vector_type(8))) __bf16 bf16x8;
typedef __attribute__((ext_vector_type(4))) float f32x4;
typedef __attribute__((ext_vector_type(4))) uint32_t u32x4;

// ---------- small helpers ----------
DEVI u16 f2b(float f) {
  __hip_bfloat16 h = __float2bfloat16(f);
  return __builtin_bit_cast(u16, h);
}
DEVI float b2f(u16 u) {
  union { float f; uint32_t i; } v;
  v.i = ((uint32_t)u) << 16;
  return v.f;
}

DEVI f32x4 mfma16(short8 a, short8 b, f32x4 c) {
  return __builtin_amdgcn_mfma_f32_16x16x32_bf16(
      __builtin_bit_cast(bf16x8, a), __builtin_bit_cast(bf16x8, b), c, 0, 0, 0);
}

// async global->LDS, 16B per lane; LDS dest = wave-uniform base + lane*16
DEVI void gload_lds16(const u16* g, u16* l) {
  __builtin_amdgcn_global_load_lds(
      (const __attribute__((address_space(1))) uint32_t*)g,
      (__attribute__((address_space(3))) uint32_t*)l, 16, 0, 0);
}

// Swizzled ds_read_b128 of an MFMA fragment from a [rows][64] bf16 tile
DEVI short8 lds_frag(const u16* base, int row, int col16) {
  int byte = (row << 7) ^ (col16 << 4) ^ ((row & 7) << 4);
  return *(const short8*)((const char*)base + byte);
}

// v_cvt_pk_bf16_f32: dst.lo = bf16(lo), dst.hi = bf16(hi)
DEVI uint32_t cvtpk(float lo, float hi) {
  uint32_t r;
  asm("v_cvt_pk_bf16_f32 %0, %1, %2" : "=v"(r) : "v"(lo), "v"(hi));
  return r;
}
// NOTE: operands must hold DISTINCT registers (same-value operands get
// register-coalesced -> self-swap -> silent corruption; round-4 bug).
DEVI void swap32(uint32_t& a, uint32_t& b) {
  asm("v_permlane32_swap_b32 %0, %1" : "+v"(a), "+v"(b));
}
DEVI void swap16(uint32_t& a, uint32_t& b) {
  asm("v_permlane16_swap_b32 %0, %1" : "+v"(a), "+v"(b));
}
// opaque copy -> guarantees a distinct register for the swap partner
DEVI uint32_t opaque_copy(uint32_t a) {
  uint32_t b;
  asm("v_mov_b32 %0, %1" : "=v"(b) : "v"(a));
  return b;
}
// max over the 4 lane-groups (lanes sharing l&15), VALU-only
DEVI float redmax64(float t) {
  uint32_t a = __builtin_bit_cast(uint32_t, t);
  uint32_t b = opaque_copy(a);
  swap16(a, b);
  float t2 = fmaxf(__builtin_bit_cast(float, a), __builtin_bit_cast(float, b));
  uint32_t c = __builtin_bit_cast(uint32_t, t2);
  uint32_t d = opaque_copy(c);
  swap32(c, d);
  return fmaxf(__builtin_bit_cast(float, c), __builtin_bit_cast(float, d));
}

// ---------- fp32 -> bf16 conversion of inputs ----------
DEVI ushort4 cvt4(float4 v) {
  ushort4 o;
  o.x = f2b(v.x); o.y = f2b(v.y); o.z = f2b(v.z); o.w = f2b(v.w);
  return o;
}

__global__ void cvt_kernel(const float4* __restrict__ x, const float4* __restrict__ wq,
                           const float4* __restrict__ wk, const float4* __restrict__ wv,
                           const float4* __restrict__ wo,
                           ushort4* __restrict__ xb, ushort4* __restrict__ wqb,
                           ushort4* __restrict__ wkb, ushort4* __restrict__ wvb,
                           ushort4* __restrict__ wob) {
  int t = blockIdx.x * blockDim.x + threadIdx.x;
  int stride = gridDim.x * blockDim.x;
  for (int i = t; i < 1048576; i += stride) xb[i]  = cvt4(x[i]);
  for (int i = t; i < 1048576; i += stride) wqb[i] = cvt4(wq[i]);
  for (int i = t; i < 262144;  i += stride) wkb[i] = cvt4(wk[i]);
  for (int i = t; i < 262144;  i += stride) wvb[i] = cvt4(wv[i]);
  for (int i = t; i < 1048576; i += stride) wob[i] = cvt4(wo[i]);
}

// ---------- QKV projection GEMM, 128x64 tile (3 blocks/CU) ----------
__global__ __launch_bounds__(256) void qkv_gemm(
    const u16* __restrict__ X, const u16* __restrict__ WQ,
    const u16* __restrict__ WK, const u16* __restrict__ WV,
    u16* __restrict__ Qo, u16* __restrict__ Ko, u16* __restrict__ VTo) {
  __shared__ __align__(16) u16 As[128 * 64];
  __shared__ __align__(16) u16 Bs[64 * 64];
  const int tid = threadIdx.x;
  const int l = tid & 63, w = tid >> 6;
  const int wm = w >> 1, wn = w & 1;
  const int bn = blockIdx.x, bm = blockIdx.y;
  const int g = l >> 4, lc = l & 15;

  const u16* Wsrc;
  int nbase;
  if (bn < 32)      { Wsrc = WQ; nbase = bn * 64; }
  else if (bn < 40) { Wsrc = WK; nbase = bn * 64 - 2048; }
  else              { Wsrc = WV; nbase = bn * 64 - 2560; }

  f32x4 acc[4][2];
#pragma unroll
  for (int i = 0; i < 4; ++i)
#pragma unroll
    for (int j = 0; j < 2; ++j) acc[i][j] = f32x4{0.f, 0.f, 0.f, 0.f};

  const u16* Abase = X + (size_t)bm * 128 * 2048;

  for (int kt = 0; kt < 32; ++kt) {
#pragma unroll
    for (int i = 0; i < 4; ++i) {
      int p = i * 256 + tid;
      int r = p >> 3;
      int c = (p & 7) ^ (r & 7);
      gload_lds16(Abase + (size_t)r * 2048 + kt * 64 + c * 8, As + p * 8);
    }
#pragma unroll
    for (int i = 0; i < 2; ++i) {
      int p = i * 256 + tid;
      int r = p >> 3;
      int c = (p & 7) ^ (r & 7);
      gload_lds16(Wsrc + (size_t)(nbase + r) * 2048 + kt * 64 + c * 8, Bs + p * 8);
    }
    __syncthreads();
#pragma unroll
    for (int kk = 0; kk < 2; ++kk) {
      short8 af[4], bfr[2];
#pragma unroll
      for (int mi = 0; mi < 4; ++mi)
        af[mi] = lds_frag(As, wm * 64 + mi * 16 + lc, kk * 4 + g);
#pragma unroll
      for (int ni = 0; ni < 2; ++ni)
        bfr[ni] = lds_frag(Bs, wn * 32 + ni * 16 + lc, kk * 4 + g);
#pragma unroll
      for (int mi = 0; mi < 4; ++mi)
#pragma unroll
        for (int ni = 0; ni < 2; ++ni)
          acc[mi][ni] = mfma16(af[mi], bfr[ni], acc[mi][ni]);
    }
    __syncthreads();
  }

#pragma unroll
  for (int mi = 0; mi < 4; ++mi) {
    int srow0 = bm * 128 + wm * 64 + mi * 16 + g * 4;
#pragma unroll
    for (int ni = 0; ni < 2; ++ni) {
      int n = nbase + wn * 32 + ni * 16 + lc;
      f32x4 v = acc[mi][ni];
      if (bn < 32) {
#pragma unroll
        for (int r = 0; r < 4; ++r)
          Qo[(size_t)(srow0 + r) * 2048 + n] = f2b(v[r]);
      } else if (bn < 40) {
#pragma unroll
        for (int r = 0; r < 4; ++r)
          Ko[(size_t)(srow0 + r) * 512 + n] = f2b(v[r]);
      } else {
        ushort4 pk;
        pk.x = f2b(v[0]); pk.y = f2b(v[1]); pk.z = f2b(v[2]); pk.w = f2b(v[3]);
        *(ushort4*)(VTo + (size_t)n * 2048 + srow0) = pk;
      }
    }
  }
}

// ---------- RoPE, vectorized short8 (4 pairs / thread; G13) ----------
__global__ void rope_kernel(u16* __restrict__ Qb, u16* __restrict__ Kb) {
  int idx = blockIdx.x * blockDim.x + threadIdx.x;
  const int NQC = 2048 * 256;
  const int NTC = NQC + 2048 * 64;
  if (idx >= NTC) return;
  u16* base;
  int s, hc;
  float scale;
  if (idx < NQC) {
    s = idx >> 8;
    int c = idx & 255;
    base = Qb + (size_t)s * 2048 + c * 8;
    hc = c & 7;
    scale = 0.18033688011112042f;  // 0.125 * log2(e) (exp2 softmax)
  } else {
    int j = idx - NQC;
    s = j >> 6;
    int c = j & 63;
    base = Kb + (size_t)s * 512 + c * 8;
    hc = c & 7;
    scale = 1.0f;
  }
  short8 v = *(const short8*)base;
  short8 ov;
  float fs = (float)s;
#pragma unroll
  for (int t = 0; t < 4; ++t) {
    float theta = exp2f(-(float)(hc * 4 + t) * 0.41524101186092034f);
    float sn, cs;
    sincosf(fs * theta, &sn, &cs);
    float x0 = b2f((u16)v[2 * t]), x1 = b2f((u16)v[2 * t + 1]);
    ov[2 * t]     = (short)f2b((x0 * cs - x1 * sn) * scale);
    ov[2 * t + 1] = (short)f2b((x1 * cs + x0 * sn) * scale);
  }
  *(short8*)base = ov;
}

// ---------- causal flash attention: 8-wave in-block split-K ----------
// grid (64, 8 kv-heads), 512 threads = 8 waves. Wave w: head kvh*4+(w&3),
// k-parity p = w>>2 (processes tiles t == p mod 2). Each block does qb = x
// then qb = 127-x sequentially; pair-iterations np(x)+np(127-x) == 17 for
// EVERY block -> uniform lifetime, 2 blocks/CU, 4 waves/SIMD throughout.
// Per iter: stage tile-pair (4 gloads/thread) double-buffered, counted
// vmcnt(4); both parity groups compute concurrently. Per-qb epilogue merges
// the two online-softmax partials (m, ls, O) in LDS (in-block flash-decode).
DEVI void stage_pair(const u16* __restrict__ Kb, const u16* __restrict__ VTb,
                     u16* base, int kvh, int t0, int t1, int tid) {
  int r = tid >> 3;
  int c = (tid & 7) ^ (r & 7);
  gload_lds16(Kb + (size_t)(t0 * 64 + r) * 512 + kvh * 64 + c * 8, base + tid * 8);
  gload_lds16(VTb + (size_t)(kvh * 64 + r) * 2048 + t0 * 64 + c * 8, base + 4096 + tid * 8);
  gload_lds16(Kb + (size_t)(t1 * 64 + r) * 512 + kvh * 64 + c * 8, base + 8192 + tid * 8);
  gload_lds16(VTb + (size_t)(kvh * 64 + r) * 2048 + t1 * 64 + c * 8, base + 12288 + tid * 8);
}

__global__ __launch_bounds__(512, 4) void attn_kernel(
    const u16* __restrict__ Qb, const u16* __restrict__ Kb,
    const u16* __restrict__ VTb, u16* __restrict__ AOb) {
  // [buf 2][tile-slot 4: K_even,V_even,K_odd,V_odd][64x64 bf16] = 64 KB
  __shared__ __align__(16) u16 S[2][4][4096];
  float* fsc = (float*)&S[0][0][0];  // combine scratch overlay (17 KB)
  // fCM0[h][q] = fsc[h*16+q]; fCM1 = +64; fCL1 = +128; fCO1[h][q][d] = +192

  const int tid = threadIdx.x;
  const int l = tid & 63, w = tid >> 6;
  const int hw = w & 3, p = w >> 2;
  const int kvh = blockIdx.y;
  const int x = blockIdx.x;
  const int h = kvh * 4 + hw;
  const int g = l >> 4, lc = l & 15;
  const short8 ONES = {16256, 16256, 16256, 16256, 16256, 16256, 16256, 16256};

  for (int half = 0; half < 2; ++half) {
    const int qb = half ? (127 - x) : x;
    const int qs = qb * 16;
    const int nt = (qb >> 2) + 1;
    const int np = (nt + 1) >> 1;

    // Q fragments (B-operand of swapped QK); issued before staging so the
    // in-loop vmcnt(4) also covers them.
    const u16* qp = Qb + (size_t)(qs + lc) * 2048 + h * 64 + g * 8;
    short8 aq0 = *(const short8*)qp;
    short8 aq1 = *(const short8*)(qp + 32);

    float m = -1e30f;
    f32x4 o[4];
    f32x4 ols = f32x4{0.f, 0.f, 0.f, 0.f};
#pragma unroll
    for (int dt = 0; dt < 4; ++dt) o[dt] = f32x4{0.f, 0.f, 0.f, 0.f};

    stage_pair(Kb, VTb, &S[0][0][0], kvh, 0, (1 < nt) ? 1 : 0, tid);

    for (int i = 0; i < np; ++i) {
      const int b = i & 1;
      // barrier1: everyone done reading buf[b^1] (prev iter) before restage
      __builtin_amdgcn_s_barrier();
      __builtin_amdgcn_sched_barrier(0);
      if (i + 1 < np) {
        int t0 = 2 * (i + 1);
        int t1 = (t0 + 1 < nt) ? (t0 + 1) : (nt - 1);  // clamp keeps count const
        stage_pair(Kb, VTb, &S[b ^ 1][0][0], kvh, t0, t1, tid);
        asm volatile("s_waitcnt vmcnt(4)" ::: "memory");  // pair(i) landed
      } else {
        asm volatile("s_waitcnt vmcnt(0)" ::: "memory");
      }
      __builtin_amdgcn_s_barrier();
      __builtin_amdgcn_sched_barrier(0);

      const int t = 2 * i + p;
      if (t < nt) {
        const u16* ks = &S[b][2 * p][0];
        const u16* vs = &S[b][2 * p + 1][0];

        // S^T[k][q] = K Q^T : lane (g,lc) holds q=lc, k = ck*16 + g*4 + r
        f32x4 s[4];
#pragma unroll
        for (int ck = 0; ck < 4; ++ck) s[ck] = f32x4{0.f, 0.f, 0.f, 0.f};
        __builtin_amdgcn_s_setprio(1);
#pragma unroll
        for (int kk = 0; kk < 2; ++kk)
#pragma unroll
          for (int ck = 0; ck < 4; ++ck) {
            short8 bk = lds_frag(ks, ck * 16 + lc, kk * 4 + g);
            s[ck] = mfma16(bk, kk ? aq1 : aq0, s[ck]);
          }
        __builtin_amdgcn_s_setprio(0);

        // causal mask on the diagonal tile
        if (t == nt - 1) {
#pragma unroll
          for (int ck = 0; ck < 4; ++ck) {
            int kg = t * 64 + ck * 16 + g * 4;
            int qg = qs + lc;
#pragma unroll
            for (int r = 0; r < 4; ++r)
              if (kg + r > qg) s[ck][r] = -1e30f;
          }
        }

        // lane-local max; full cross-lane reduce only on (rare) rescale
        float t0m = fmaxf(fmaxf(s[0][0], s[0][1]), fmaxf(s[0][2], s[0][3]));
        float t1m = fmaxf(fmaxf(s[1][0], s[1][1]), fmaxf(s[1][2], s[1][3]));
        float t2m = fmaxf(fmaxf(s[2][0], s[2][1]), fmaxf(s[2][2], s[2][3]));
        float t3m = fmaxf(fmaxf(s[3][0], s[3][1]), fmaxf(s[3][2], s[3][3]));
        float lm = fmaxf(fmaxf(t0m, t1m), fmaxf(t2m, t3m));
        if (!__all(lm <= m + 8.f)) {
          float tmax = redmax64(lm);
          float mn = fmaxf(m, tmax);
          float al = exp2f(m - mn);
          m = mn;
#pragma unroll
          for (int r = 0; r < 4; ++r) {
            float alr = __shfl(al, g * 4 + r);  // col->row layout
            ols[r] *= alr;
#pragma unroll
            for (int dt = 0; dt < 4; ++dt) o[dt][r] *= alr;
          }
        }

        // P = exp2(S - m); pack to PV A-frags in-register (cvt_pk+permlane)
        short8 pfrag[2];
        {
          uint32_t d0[4], d1[4];
#pragma unroll
          for (int ck = 0; ck < 4; ++ck) {
            float e0 = exp2f(s[ck][0] - m);
            float e1 = exp2f(s[ck][1] - m);
            float e2 = exp2f(s[ck][2] - m);
            float e3 = exp2f(s[ck][3] - m);
            d0[ck] = cvtpk(e0, e1);
            d1[ck] = cvtpk(e2, e3);
          }
#pragma unroll
          for (int kk = 0; kk < 2; ++kk) {
            uint32_t A0 = d0[2 * kk], B0 = d0[2 * kk + 1];
            swap32(A0, B0); swap16(A0, B0);
            uint32_t A1 = d1[2 * kk], B1 = d1[2 * kk + 1];
            swap32(A1, B1); swap16(A1, B1);
            u32x4 u = {A0, A1, B0, B1};
            pfrag[kk] = __builtin_bit_cast(short8, u);
          }
        }

        // O += P V ; ls += P * ones (row layout)
        __builtin_amdgcn_s_setprio(1);
#pragma unroll
        for (int kk = 0; kk < 2; ++kk) {
#pragma unroll
          for (int dt = 0; dt < 4; ++dt) {
            short8 bv = lds_frag(vs, dt * 16 + lc, kk * 4 + g);
            o[dt] = mfma16(pfrag[kk], bv, o[dt]);
          }
          ols = mfma16(pfrag[kk], ONES, ols);
        }
        __builtin_amdgcn_s_setprio(0);
      }
    }

    // ---- in-block combine of the two k-parity partials ----
    __builtin_amdgcn_s_barrier();  // all compute (incl. reads of S) done
    if (p == 1) {
      if (g == 0) fsc[64 + hw * 16 + lc] = m;                    // fCM1
      if (lc == 0) {
#pragma unroll
        for (int r = 0; r < 4; ++r) fsc[128 + hw * 16 + g * 4 + r] = ols[r];  // fCL1
      }
#pragma unroll
      for (int dt = 0; dt < 4; ++dt)
#pragma unroll
        for (int r = 0; r < 4; ++r)
          fsc[192 + (hw * 16 + g * 4 + r) * 64 + dt * 16 + lc] = o[dt][r];    // fCO1
    } else {
      if (g == 0) fsc[hw * 16 + lc] = m;                         // fCM0
    }
    __builtin_amdgcn_s_barrier();
    if (p == 0) {
#pragma unroll
      for (int r = 0; r < 4; ++r) {
        int q = g * 4 + r;
        float m0 = fsc[hw * 16 + q];
        float m1 = fsc[64 + hw * 16 + q];
        float M = fmaxf(m0, m1);
        float a0 = exp2f(m0 - M);
        float a1 = exp2f(m1 - M);
        float den = ols[r] * a0 + fsc[128 + hw * 16 + q] * a1;
        float inv = 1.0f / den;
#pragma unroll
        for (int dt = 0; dt < 4; ++dt) {
          float v = (o[dt][r] * a0 +
                     fsc[192 + (hw * 16 + q) * 64 + dt * 16 + lc] * a1) * inv;
          AOb[(size_t)(qs + q) * 2048 + h * 64 + dt * 16 + lc] = f2b(v);
        }
      }
    }
    __builtin_amdgcn_s_barrier();  // scratch reads done before next half stages
  }
}

// ---------- output projection GEMM, 128x64 tile (2 blocks/CU) ----------
__global__ __launch_bounds__(256) void out_gemm(
    const u16* __restrict__ A, const u16* __restrict__ W, float* __restrict__ C) {
  __shared__ __align__(16) u16 As[128 * 64];
  __shared__ __align__(16) u16 Bs[64 * 64];
  const int tid = threadIdx.x;
  const int l = tid & 63, w = tid >> 6;
  const int wm = w >> 1, wn = w & 1;
  const int bn = blockIdx.x, bm = blockIdx.y;
  const int g = l >> 4, lc = l & 15;

  f32x4 acc[4][2];
#pragma unroll
  for (int i = 0; i < 4; ++i)
#pragma unroll
    for (int j = 0; j < 2; ++j) acc[i][j] = f32x4{0.f, 0.f, 0.f, 0.f};

  const u16* Abase = A + (size_t)bm * 128 * 2048;
  const u16* Bbase = W + (size_t)bn * 64 * 2048;

  for (int kt = 0; kt < 32; ++kt) {
#pragma unroll
    for (int i = 0; i < 4; ++i) {
      int p = i * 256 + tid;
      int r = p >> 3;
      int c = (p & 7) ^ (r & 7);
      gload_lds16(Abase + (size_t)r * 2048 + kt * 64 + c * 8, As + p * 8);
    }
#pragma unroll
    for (int i = 0; i < 2; ++i) {
      int p = i * 256 + tid;
      int r = p >> 3;
      int c = (p & 7) ^ (r & 7);
      gload_lds16(Bbase + (size_t)r * 2048 + kt * 64 + c * 8, Bs + p * 8);
    }
    __syncthreads();
#pragma unroll
    for (int kk = 0; kk < 2; ++kk) {
      short8 af[4], bfr[2];
#pragma unroll
      for (int mi = 0; mi < 4; ++mi)
        af[mi] = lds_frag(As, wm * 64 + mi * 16 + lc, kk * 4 + g);
#pragma unroll
      for (int ni = 0; ni < 2; ++ni)
        bfr[ni] = lds_frag(Bs, wn * 32 + ni * 16 + lc, kk * 4 + g);
#pragma unroll
      for (int mi = 0; mi < 4; ++mi)
#pragma unroll
        for (int ni = 0; ni < 2; ++ni)
          acc[mi][ni] = mfma16(af[mi], bfr[ni], acc[mi][ni]);
    }
    __syncthreads();
  }

#pragma unroll
  for (int mi = 0; mi < 4; ++mi) {
    int srow0 = bm * 128 + wm * 64 + mi * 16 + g * 4;
#pragma unroll
    for (int ni = 0; ni < 2; ++ni) {
      int n = bn * 64 + wn * 32 + ni * 16 + lc;
#pragma unroll
      for (int r = 0; r < 4; ++r)
        C[(size_t)(srow0 + r) * 2048 + n] = acc[mi][ni][r];
    }
  }
}

// ---------- launch ----------
extern "C" void kernel_launch(void* const* d_in, const int* in_sizes, int n_in,
                              void* d_out, int out_size, void* d_ws, size_t ws_size,
                              hipStream_t stream) {
  (void)in_sizes; (void)n_in; (void)out_size; (void)ws_size;
  const float* x  = (const float*)d_in[0];
  const float* wq = (const float*)d_in[1];
  const float* wk = (const float*)d_in[2];
  const float* wv = (const float*)d_in[3];
  const float* wo = (const float*)d_in[4];
  float* out = (float*)d_out;
  char* ws = (char*)d_ws;

  u16* xbf  = (u16*)(ws + 0);
  u16* wqbf = (u16*)(ws + 8388608);
  u16* wkbf = (u16*)(ws + 16777216);
  u16* wvbf = (u16*)(ws + 18874368);
  u16* wobf = (u16*)(ws + 20971520);
  u16* Qb   = (u16*)(ws + 29360128);
  u16* Kb   = (u16*)(ws + 37748736);
  u16* VTb  = (u16*)(ws + 39845888);
  u16* AOb  = (u16*)(ws + 41943040);

  cvt_kernel<<<2048, 256, 0, stream>>>(
      (const float4*)x, (const float4*)wq, (const float4*)wk,
      (const float4*)wv, (const float4*)wo,
      (ushort4*)xbf, (ushort4*)wqbf, (ushort4*)wkbf, (ushort4*)wvbf, (ushort4*)wobf);

  qkv_gemm<<<dim3(48, 16), 256, 0, stream>>>(xbf, wqbf, wkbf, wvbf, Qb, Kb, VTb);

  rope_kernel<<<(2048 * 256 + 2048 * 64 + 255) / 256, 256, 0, stream>>>(Qb, Kb);

  attn_kernel<<<dim3(64, 8), 512, 0, stream>>>(Qb, Kb, VTb, AOb);

  out_gemm<<<dim3(32, 16), 256, 0, stream>>>(AOb, wobf, out);
}